// Round 12
// baseline (31311.362 us; speedup 1.0000x reference)
//
#include <hip/hip_runtime.h>
#include <string.h>
#include <math.h>

#define NE 100000
#define NN 8192
#define NG 512
#define CHF 25000
#define NF 4
#define CHB 20000
#define NB 5
#define CHIF 50000
#define NIF 2
#define CHIB 34000
#define NIB 3
#define NNC 8192

#define SQ3F  1.7320508075688772f
#define SQ5F  2.23606797749979f
#define SQ15F 3.872983346207417f

__constant__ int c_amap[10] = {-1,0,-1,-1,-1,-1,1,2,3,4};

typedef __attribute__((ext_vector_type(4))) float f32x4;
typedef __attribute__((ext_vector_type(8))) short bf16x8;

__device__ __forceinline__ float sigf(float x){ return 1.0f/(1.0f+expf(-x)); }
__device__ __forceinline__ float siluf(float x){ return x*sigf(x); }
__device__ __forceinline__ float dsiluf(float x){ float s=sigf(x); return s*(1.0f + x*(1.0f-s)); }

__device__ __forceinline__ float wred64(float v){
  #pragma unroll
  for (int o=32;o>0;o>>=1) v += __shfl_down(v,o,64);
  return v;
}
__device__ __forceinline__ int lbound(const int* a, int n, int v){
  int lo=0, hi=n;
  while (lo<hi){ int m=(lo+hi)>>1; if (a[m]<v) lo=m+1; else hi=m; }
  return lo;
}
__device__ __forceinline__ unsigned short f2b(float x){
  unsigned u=__float_as_uint(x);
  unsigned r=(u + 0x7fffu + ((u>>16)&1u))>>16;
  return (unsigned short)r;
}
__device__ __forceinline__ float b2f(unsigned short b){
  return __uint_as_float(((unsigned)b)<<16);
}

// ---------------- edge sort by dst (counting sort) ----------------
__global__ void k_hist(const int* keys, int* hist, int n){
  int i = blockIdx.x*256 + threadIdx.x;
  if (i < n) atomicAdd(&hist[keys[i]], 1);
}
__global__ __launch_bounds__(256) void k_scan0(const int* hist, int* rows){
  __shared__ int part[256];
  int t = threadIdx.x;
  int base = t*32;
  int loc[32];
  int s = 0;
  #pragma unroll
  for (int i=0;i<32;i++){ loc[i]=s; s+=hist[base+i]; }
  part[t]=s;
  __syncthreads();
  int pre=0;
  for (int i=0;i<t;i++) pre+=part[i];
  #pragma unroll
  for (int i=0;i<32;i++) rows[base+i]=pre+loc[i];
  if (t==255) rows[NN]=pre+s;
}
__global__ void k_fillperm(const int* keys, int* cursor, int* perm, int n){
  int i = blockIdx.x*256 + threadIdx.x;
  if (i < n){
    int slot = atomicAdd(&cursor[keys[i]], 1);
    perm[slot] = i;
  }
}
__global__ void k_mkedge(const int* perm, const int* src, const int* dst, int* src2, int* dst2){
  int k = blockIdx.x*256 + threadIdx.x;
  if (k < NE){ int e = perm[k]; src2[k] = src[e]; dst2[k] = dst[e]; }
}

// weight concat: WCATF[i][k][0:352] = [Wv0 | Ws0 | Ws1 | Ws2]
__global__ void k_wcat(const float* Wv0,const float* Ws0,const float* Ws1,const float* Ws2, float* W){
  int t = blockIdx.x*256 + threadIdx.x;
  if (t >= 8*128*352) return;
  int i = t/45056, r = t - i*45056;
  int k = r/352, n = r - k*352;
  float v;
  if (n < 128) v = Wv0[(size_t)i*16384 + k*128 + n];
  else if (n < 256) v = Ws0[(size_t)i*16384 + k*128 + (n-128)];
  else if (n < 320) v = Ws1[(size_t)i*8192 + k*64 + (n-256)];
  else v = Ws2[(size_t)i*4096 + k*32 + (n-320)];
  W[t] = v;
}
// attention weight concat: WCATZ[i][k][0:32], k in [0,320) = [WaS ; WaD ; WaE]
__global__ void k_wcatz(const float* WaS,const float* WaD,const float* WaE, float* W){
  int t = blockIdx.x*256 + threadIdx.x;
  if (t >= 8*320*32) return;
  int i = t/10240, r = t - i*10240;
  int k = r/32, c = r - k*32;
  float v;
  if (k < 128) v = WaS[(size_t)i*4096 + k*32 + c];
  else if (k < 256) v = WaD[(size_t)i*4096 + (k-128)*32 + c];
  else v = WaE[(size_t)i*2048 + (k-256)*32 + c];
  W[t] = v;
}
// gate weight concat: WCATG[i][k][0:96] = [fg1 | fg2]
__global__ void k_wcatg(const float* fg1,const float* fg2, float* W){
  int t = blockIdx.x*256 + threadIdx.x;
  if (t >= 8*128*96) return;
  int i = t/12288, r = t - i*12288;
  int k = r/96, c = r - k*96;
  float v;
  if (c < 64) v = fg1[(size_t)i*8192 + k*64 + c];
  else v = fg2[(size_t)i*4096 + k*32 + (c-64)];
  W[t] = v;
}

// --- bf16 MFMA GEMM; MT = M-tile; SPLIT=3-term split-bf16; ARBF=A computed as RBF(Rr row);
//     DMUL=epilogue *dsilu(dm); PREOUT=write pre-activation to pre[]; Dacc: accumulator source (else C) ---
template<int MT, bool TB, bool ACC, int ACT, bool GATHER, bool SPLIT, bool ARBF, bool DMUL, bool PREOUT>
__global__ __launch_bounds__(256) void k_mgemm(
    const float* __restrict__ A, const int* __restrict__ idx,
    const float* __restrict__ B, float* __restrict__ C,
    int M, int Nd, int K,
    const float* __restrict__ cen, const float* __restrict__ wid,
    const float* __restrict__ dm, float* __restrict__ pre, const float* __restrict__ Dacc)
{
  constexpr int TPR = 256/MT;     // threads per A-row
  constexpr int EPT = 32/TPR;     // elems per thread (A staging)
  constexpr int RT  = MT/16;      // MFMA row-tiles
  __shared__ unsigned short Asb[(SPLIT?2:1)*MT*40];
  __shared__ unsigned short Btb[(SPLIT?2:1)*2560];
  const int bm = blockIdx.x*MT, bn = blockIdx.y*64;
  const int tid = threadIdx.x;
  const int wave = tid>>6, lane = tid&63;
  const int arow_s = tid / TPR, aoff = (tid % TPR) * EPT;
  const int bsrow = tid>>2, bsoff = (tid&3)*8;
  f32x4 acc[RT];
  #pragma unroll
  for (int r=0;r<RT;r++) acc[r] = (f32x4){0.f,0.f,0.f,0.f};
  int arow = -1;
  {
    int gr = bm + arow_s;
    if (gr < M) arow = GATHER ? idx[gr] : gr;
  }
  int bcol = bn + bsrow;
  for (int k0=0;k0<K;k0+=32){
    #pragma unroll
    for (int i=0;i<EPT;i++){
      float v = 0.0f;
      if (arow>=0){
        if (ARBF){
          float r = A[arow];
          int kk = k0 + aoff + i;
          float t = (r - cen[kk]) / wid[kk];
          v = expf(-0.5f*t*t);
        } else {
          v = A[(size_t)arow*K + k0 + aoff + i];
        }
      }
      unsigned short h = f2b(v);
      Asb[arow_s*40 + aoff + i] = h;
      if (SPLIT) Asb[MT*40 + arow_s*40 + aoff + i] = f2b(v - b2f(h));
    }
    #pragma unroll
    for (int i=0;i<8;i++){
      float v = 0.0f;
      if (bcol < Nd) v = TB ? B[(size_t)bcol*K + k0 + bsoff + i] : B[(size_t)(k0+bsoff+i)*Nd + bcol];
      unsigned short h = f2b(v);
      Btb[bsrow*40 + bsoff + i] = h;
      if (SPLIT) Btb[2560 + bsrow*40 + bsoff + i] = f2b(v - b2f(h));
    }
    __syncthreads();
    int boff = (wave*16 + (lane&15))*40 + (lane>>4)*8;
    bf16x8 bh = *(const bf16x8*)&Btb[boff];
    #pragma unroll
    for (int r=0;r<RT;r++){
      int aoff2 = (r*16 + (lane&15))*40 + (lane>>4)*8;
      bf16x8 ah = *(const bf16x8*)&Asb[aoff2];
      acc[r] = __builtin_amdgcn_mfma_f32_16x16x32_bf16(ah, bh, acc[r], 0,0,0);
      if (SPLIT){
        bf16x8 bl = *(const bf16x8*)&Btb[2560 + boff];
        bf16x8 al = *(const bf16x8*)&Asb[MT*40 + aoff2];
        acc[r] = __builtin_amdgcn_mfma_f32_16x16x32_bf16(ah, bl, acc[r], 0,0,0);
        acc[r] = __builtin_amdgcn_mfma_f32_16x16x32_bf16(al, bh, acc[r], 0,0,0);
      }
    }
    __syncthreads();
  }
  int col = bn + wave*16 + (lane&15);
  if (col < Nd){
    #pragma unroll
    for (int r=0;r<RT;r++){
      #pragma unroll
      for (int v=0;v<4;v++){
        int row = bm + r*16 + (lane>>4)*4 + v;
        if (row >= M) continue;
        size_t o = (size_t)row*Nd + col;
        float x = acc[r][v];
        if (ACC) x += (Dacc ? Dacc[o] : C[o]);
        if (DMUL) x *= dsiluf(dm[o]);
        if (PREOUT) pre[o] = x;
        if (ACT == 1) x = siluf(x);
        else if (ACT == 2) x = tanhf(x);
        else if (ACT == 3) x = sigf(x);
        C[o] = x;
      }
    }
  }
}

// --- fused radial MLP: H2 = silu( silu(RBF@W1) @ W2 ); PRE: also write pre-activations.
//     Bit-identical to the unfused pair: H1 is silu'ed, f2b-quantized (hi/lo for SPLIT) exactly
//     as the second GEMM's A-staging would do. M-tile 64, K1=128, N1=K2=N2=64. ---
template<bool SPLIT, bool PRE>
__global__ __launch_bounds__(256) void k_mlp2(
    const float* __restrict__ Rr, const float* __restrict__ cen, const float* __restrict__ wid,
    const float* __restrict__ W1, const float* __restrict__ W2,
    float* __restrict__ H2o, float* __restrict__ PRE1, float* __restrict__ PRE2, int M)
{
  __shared__ unsigned short Asb[(SPLIT?2:1)*2560];
  __shared__ unsigned short Btb[(SPLIT?2:1)*2560];
  __shared__ unsigned short As2[(SPLIT?2:1)*5120];   // H1 bf16: [kstep][row*40 + k%32]
  const int bm = blockIdx.x*64;
  const int tid = threadIdx.x, wave = tid>>6, lane = tid&63;
  const int arow_s = tid>>2, aoff = (tid&3)*8;
  const int bsrow = tid>>2, bsoff = (tid&3)*8;
  f32x4 acc[4];
  #pragma unroll
  for (int r=0;r<4;r++) acc[r] = (f32x4){0.f,0.f,0.f,0.f};
  int arow = -1;
  { int gr = bm + arow_s; if (gr < M) arow = gr; }
  float rv = (arow>=0) ? Rr[arow] : 0.0f;
  // ---- phase 1: H1 = RBF @ W1 ----
  for (int k0=0;k0<128;k0+=32){
    #pragma unroll
    for (int i=0;i<8;i++){
      float v = 0.0f;
      if (arow>=0){
        int kk = k0 + aoff + i;
        float t = (rv - cen[kk]) / wid[kk];
        v = expf(-0.5f*t*t);
      }
      unsigned short h = f2b(v);
      Asb[arow_s*40 + aoff + i] = h;
      if (SPLIT) Asb[2560 + arow_s*40 + aoff + i] = f2b(v - b2f(h));
    }
    #pragma unroll
    for (int i=0;i<8;i++){
      float v = W1[(size_t)(k0+bsoff+i)*64 + bsrow];
      unsigned short h = f2b(v);
      Btb[bsrow*40 + bsoff + i] = h;
      if (SPLIT) Btb[2560 + bsrow*40 + bsoff + i] = f2b(v - b2f(h));
    }
    __syncthreads();
    int boff = (wave*16 + (lane&15))*40 + (lane>>4)*8;
    bf16x8 bh = *(const bf16x8*)&Btb[boff];
    #pragma unroll
    for (int r=0;r<4;r++){
      int aoff2 = (r*16 + (lane&15))*40 + (lane>>4)*8;
      bf16x8 ah = *(const bf16x8*)&Asb[aoff2];
      acc[r] = __builtin_amdgcn_mfma_f32_16x16x32_bf16(ah, bh, acc[r], 0,0,0);
      if (SPLIT){
        bf16x8 bl = *(const bf16x8*)&Btb[2560 + boff];
        bf16x8 al = *(const bf16x8*)&Asb[2560 + aoff2];
        acc[r] = __builtin_amdgcn_mfma_f32_16x16x32_bf16(ah, bl, acc[r], 0,0,0);
        acc[r] = __builtin_amdgcn_mfma_f32_16x16x32_bf16(al, bh, acc[r], 0,0,0);
      }
    }
    __syncthreads();
  }
  // ---- epilogue 1: silu (+PRE1) -> pack H1 into As2 (exactly the old restaging quantization) ----
  {
    int col = wave*16 + (lane&15);
    #pragma unroll
    for (int r=0;r<4;r++){
      #pragma unroll
      for (int v=0;v<4;v++){
        int lrow = r*16 + (lane>>4)*4 + v;
        int row = bm + lrow;
        float x = acc[r][v];
        if (PRE && row < M) PRE1[(size_t)row*64 + col] = x;
        x = siluf(x);
        unsigned short h = f2b(x);
        As2[(col>>5)*2560 + lrow*40 + (col&31)] = h;
        if (SPLIT) As2[5120 + (col>>5)*2560 + lrow*40 + (col&31)] = f2b(x - b2f(h));
        acc[r][v] = 0.0f;
      }
    }
  }
  __syncthreads();
  // ---- phase 2: H2 = H1 @ W2 ----
  for (int k0=0;k0<64;k0+=32){
    #pragma unroll
    for (int i=0;i<8;i++){
      float v = W2[(size_t)(k0+bsoff+i)*64 + bsrow];
      unsigned short h = f2b(v);
      Btb[bsrow*40 + bsoff + i] = h;
      if (SPLIT) Btb[2560 + bsrow*40 + bsoff + i] = f2b(v - b2f(h));
    }
    __syncthreads();
    int boff = (wave*16 + (lane&15))*40 + (lane>>4)*8;
    bf16x8 bh = *(const bf16x8*)&Btb[boff];
    int ksel = (k0>>5)*2560;
    #pragma unroll
    for (int r=0;r<4;r++){
      int aoff2 = ksel + (r*16 + (lane&15))*40 + (lane>>4)*8;
      bf16x8 ah = *(const bf16x8*)&As2[aoff2];
      acc[r] = __builtin_amdgcn_mfma_f32_16x16x32_bf16(ah, bh, acc[r], 0,0,0);
      if (SPLIT){
        bf16x8 bl = *(const bf16x8*)&Btb[2560 + boff];
        bf16x8 al = *(const bf16x8*)&As2[5120 + aoff2];
        acc[r] = __builtin_amdgcn_mfma_f32_16x16x32_bf16(ah, bl, acc[r], 0,0,0);
        acc[r] = __builtin_amdgcn_mfma_f32_16x16x32_bf16(al, bh, acc[r], 0,0,0);
      }
    }
    __syncthreads();
  }
  // ---- epilogue 2 ----
  {
    int col = wave*16 + (lane&15);
    #pragma unroll
    for (int r=0;r<4;r++){
      #pragma unroll
      for (int v=0;v<4;v++){
        int row = bm + r*16 + (lane>>4)*4 + v;
        if (row >= M) continue;
        float x = acc[r][v];
        if (PRE) PRE2[(size_t)row*64 + col] = x;
        H2o[(size_t)row*64 + col] = siluf(x);
      }
    }
  }
}

// --- fused backward radial chain: dH2 = (ACC? Hpart[o] + :)(DGc@W3^T); dH2 *= dsilu(PRE2);
//     dH1 = (dH2 @ W2^T) * dsilu(PRE1) -> H1o.  Both phases Nd=64, grid-preserving.
//     Bit-identical to the unfused pair: dH2 is f2b-quantized exactly as the standalone
//     second GEMM's A-staging would quantize the f32 it read back from global. ---
template<bool ACC>
__global__ __launch_bounds__(256) void k_bmlp2(
    const float* __restrict__ DGc, const float* __restrict__ W3, const float* __restrict__ W2,
    const float* __restrict__ Hpart, const float* __restrict__ PRE2, const float* __restrict__ PRE1,
    float* __restrict__ H1o, int M)
{
  __shared__ unsigned short Asb[2560];
  __shared__ unsigned short Btb[2560];
  __shared__ unsigned short As2[5120];
  const int bm = blockIdx.x*64;
  const int tid = threadIdx.x, wave = tid>>6, lane = tid&63;
  const int arow_s = tid>>2, aoff = (tid&3)*8;
  const int bsrow = tid>>2, bsoff = (tid&3)*8;
  f32x4 acc[4];
  #pragma unroll
  for (int r=0;r<4;r++) acc[r] = (f32x4){0.f,0.f,0.f,0.f};
  int arow = -1;
  { int gr = bm + arow_s; if (gr < M) arow = gr; }
  // ---- phase A: dH2 = DGc @ W3^T (K=224) ----
  for (int k0=0;k0<224;k0+=32){
    #pragma unroll
    for (int i=0;i<8;i++){
      float v = (arow>=0) ? DGc[(size_t)arow*224 + k0 + aoff + i] : 0.0f;
      Asb[arow_s*40 + aoff + i] = f2b(v);
    }
    #pragma unroll
    for (int i=0;i<8;i++){
      float v = W3[(size_t)bsrow*224 + k0 + bsoff + i];
      Btb[bsrow*40 + bsoff + i] = f2b(v);
    }
    __syncthreads();
    int boff = (wave*16 + (lane&15))*40 + (lane>>4)*8;
    bf16x8 bh = *(const bf16x8*)&Btb[boff];
    #pragma unroll
    for (int r=0;r<4;r++){
      int aoff2 = (r*16 + (lane&15))*40 + (lane>>4)*8;
      bf16x8 ah = *(const bf16x8*)&Asb[aoff2];
      acc[r] = __builtin_amdgcn_mfma_f32_16x16x32_bf16(ah, bh, acc[r], 0,0,0);
    }
    __syncthreads();
  }
  // ---- epilogue A: (+Hpart) * dsilu(PRE2) -> pack into As2 ----
  {
    int col = wave*16 + (lane&15);
    #pragma unroll
    for (int r=0;r<4;r++){
      #pragma unroll
      for (int v=0;v<4;v++){
        int lrow = r*16 + (lane>>4)*4 + v;
        int row = bm + lrow;
        float x = acc[r][v];
        if (row < M){
          size_t o = (size_t)row*64 + col;
          if (ACC) x += Hpart[o];
          x *= dsiluf(PRE2[o]);
        } else {
          x = 0.0f;
        }
        As2[(col>>5)*2560 + lrow*40 + (col&31)] = f2b(x);
        acc[r][v] = 0.0f;
      }
    }
  }
  __syncthreads();
  // ---- phase B: dH1 = dH2 @ W2^T (K=64) ----
  for (int k0=0;k0<64;k0+=32){
    #pragma unroll
    for (int i=0;i<8;i++){
      float v = W2[(size_t)bsrow*64 + k0 + bsoff + i];
      Btb[bsrow*40 + bsoff + i] = f2b(v);
    }
    __syncthreads();
    int boff = (wave*16 + (lane&15))*40 + (lane>>4)*8;
    bf16x8 bh = *(const bf16x8*)&Btb[boff];
    int ksel = (k0>>5)*2560;
    #pragma unroll
    for (int r=0;r<4;r++){
      int aoff2 = ksel + (r*16 + (lane&15))*40 + (lane>>4)*8;
      bf16x8 ah = *(const bf16x8*)&As2[aoff2];
      acc[r] = __builtin_amdgcn_mfma_f32_16x16x32_bf16(ah, bh, acc[r], 0,0,0);
    }
    __syncthreads();
  }
  // ---- epilogue B ----
  {
    int col = wave*16 + (lane&15);
    #pragma unroll
    for (int r=0;r<4;r++){
      #pragma unroll
      for (int v=0;v<4;v++){
        int row = bm + r*16 + (lane>>4)*4 + v;
        if (row >= M) continue;
        size_t o = (size_t)row*64 + col;
        H1o[o] = acc[r][v] * dsiluf(PRE1[o]);
      }
    }
  }
}

// --- fused attention-logit GEMM: Zc = tanh([f0[src]|f0[dst]|H2] @ WZ) (K=320, Nd=32)
//     LAMB: also LAM[row] = exp( sum_c Zc[row][c]*wa[c] ) ---
template<bool SPLIT, bool LAMB>
__global__ __launch_bounds__(256) void k_zgemm(
    const float* __restrict__ F0, const int* __restrict__ sidx, const int* __restrict__ didx,
    const float* __restrict__ H2v, const float* __restrict__ WZ, const float* __restrict__ wa,
    float* __restrict__ Zc, float* __restrict__ LAM, int M)
{
  __shared__ unsigned short Asb[(SPLIT?2:1)*64*40];
  __shared__ unsigned short Btb[(SPLIT?2:1)*2560];
  __shared__ float lacc[128];
  const int bm = blockIdx.x*64;
  const int tid = threadIdx.x, wave = tid>>6, lane = tid&63;
  const int arow_s = tid>>2, aoff = (tid&3)*8;
  const int bsrow = tid>>2, bsoff = (tid&3)*8;
  f32x4 acc[4];
  #pragma unroll
  for (int r=0;r<4;r++) acc[r] = (f32x4){0.f,0.f,0.f,0.f};
  long sb=-1, db=-1, hb=-1;
  {
    int gr = bm + arow_s;
    if (gr < M){ sb=(long)sidx[gr]*128; db=(long)didx[gr]*128; hb=(long)gr*64; }
  }
  for (int k0=0;k0<320;k0+=32){
    long ab; int rk; const float* sp;
    if (k0 < 128){ ab=sb; rk=k0; sp=F0; }
    else if (k0 < 256){ ab=db; rk=k0-128; sp=F0; }
    else { ab=hb; rk=k0-256; sp=H2v; }
    #pragma unroll
    for (int i=0;i<8;i++){
      float v = (ab>=0) ? sp[ab + rk + aoff + i] : 0.0f;
      unsigned short h = f2b(v);
      Asb[arow_s*40 + aoff + i] = h;
      if (SPLIT) Asb[64*40 + arow_s*40 + aoff + i] = f2b(v - b2f(h));
    }
    #pragma unroll
    for (int i=0;i<8;i++){
      int kk = k0 + bsoff + i;
      float v = (bsrow < 32) ? WZ[kk*32 + bsrow] : 0.0f;
      unsigned short h = f2b(v);
      Btb[bsrow*40 + bsoff + i] = h;
      if (SPLIT) Btb[2560 + bsrow*40 + bsoff + i] = f2b(v - b2f(h));
    }
    __syncthreads();
    int boff = (wave*16 + (lane&15))*40 + (lane>>4)*8;
    bf16x8 bh = *(const bf16x8*)&Btb[boff];
    #pragma unroll
    for (int r=0;r<4;r++){
      int aoff2 = (r*16 + (lane&15))*40 + (lane>>4)*8;
      bf16x8 ah = *(const bf16x8*)&Asb[aoff2];
      acc[r] = __builtin_amdgcn_mfma_f32_16x16x32_bf16(ah, bh, acc[r], 0,0,0);
      if (SPLIT){
        bf16x8 bl = *(const bf16x8*)&Btb[2560 + boff];
        bf16x8 al = *(const bf16x8*)&Asb[64*40 + aoff2];
        acc[r] = __builtin_amdgcn_mfma_f32_16x16x32_bf16(ah, bl, acc[r], 0,0,0);
        acc[r] = __builtin_amdgcn_mfma_f32_16x16x32_bf16(al, bh, acc[r], 0,0,0);
      }
    }
    __syncthreads();
  }
  int col = wave*16 + (lane&15);
  if (wave < 2){   // cols 0..31
    #pragma unroll
    for (int r=0;r<4;r++){
      #pragma unroll
      for (int v=0;v<4;v++){
        int row = bm + r*16 + (lane>>4)*4 + v;
        float z = tanhf(acc[r][v]);
        if (row < M) Zc[(size_t)row*32 + col] = z;
        if (LAMB){
          float p = (row < M) ? z*wa[col] : 0.0f;
          #pragma unroll
          for (int o=8;o>0;o>>=1) p += __shfl_xor(p, o, 64);
          if ((lane&15)==0) lacc[wave*64 + r*16 + (lane>>4)*4 + v] = p;
        }
      }
    }
  }
  if (LAMB){
    __syncthreads();
    if (tid < 64){
      int row = bm + tid;
      if (row < M) LAM[row] = expf(lacc[tid] + lacc[64+tid]);
    }
  }
}

// ---------- bf16 MFMA einsum (X-strided rows); SPLIT => split-bf16; GATE: C[o]=A[o]+x*P; Dacc acc source ----------
template<int CI, int CO, int X, bool TB, bool ACC, bool GATHER, bool SPLIT, bool GATE>
__global__ __launch_bounds__(256) void k_meinsum(
    const float* __restrict__ A, const int* __restrict__ idx,
    const float* __restrict__ W, float* __restrict__ C, int M,
    const float* __restrict__ P, int PS, int POFF, const float* __restrict__ Dacc)
{
  __shared__ unsigned short Asb[(SPLIT?2:1)*2560];
  __shared__ unsigned short Btb[(SPLIT?2:1)*2560];
  const int bm = blockIdx.x*64;
  const int tid = threadIdx.x, wave = tid>>6, lane = tid&63;
  const int srow = tid>>2, soff = (tid&3)*8;
  f32x4 acc[4];
  #pragma unroll
  for (int r=0;r<4;r++) acc[r] = (f32x4){0.f,0.f,0.f,0.f};
  long abase = -1;
  {
    int grow = bm + srow;
    if (grow < M*X){
      int ge = grow / X, gx = grow - ge*X;
      int ar = GATHER ? idx[ge] : ge;
      abase = (long)ar*CI*X + gx;
    }
  }
  for (int k0=0;k0<CI;k0+=32){
    #pragma unroll
    for (int i=0;i<8;i++){
      float v = (abase>=0) ? A[abase + (size_t)(k0+soff+i)*X] : 0.0f;
      unsigned short h = f2b(v);
      Asb[srow*40 + soff + i] = h;
      if (SPLIT) Asb[2560 + srow*40 + soff + i] = f2b(v - b2f(h));
    }
    #pragma unroll
    for (int i=0;i<8;i++){
      int kk = k0 + soff + i;
      float v = 0.0f;
      if (srow < CO) v = TB ? W[srow*CI + kk] : W[kk*CO + srow];
      unsigned short h = f2b(v);
      Btb[srow*40 + soff + i] = h;
      if (SPLIT) Btb[2560 + srow*40 + soff + i] = f2b(v - b2f(h));
    }
    __syncthreads();
    int boff = (wave*16 + (lane&15))*40 + (lane>>4)*8;
    bf16x8 bh = *(const bf16x8*)&Btb[boff];
    #pragma unroll
    for (int r=0;r<4;r++){
      int aoff = (r*16 + (lane&15))*40 + (lane>>4)*8;
      bf16x8 ah = *(const bf16x8*)&Asb[aoff];
      acc[r] = __builtin_amdgcn_mfma_f32_16x16x32_bf16(ah, bh, acc[r], 0,0,0);
      if (SPLIT){
        bf16x8 bl = *(const bf16x8*)&Btb[2560 + boff];
        bf16x8 al = *(const bf16x8*)&Asb[2560 + aoff];
        acc[r] = __builtin_amdgcn_mfma_f32_16x16x32_bf16(ah, bl, acc[r], 0,0,0);
        acc[r] = __builtin_amdgcn_mfma_f32_16x16x32_bf16(al, bh, acc[r], 0,0,0);
      }
    }
    __syncthreads();
  }
  int col = wave*16 + (lane&15);
  if (col < CO){
    #pragma unroll
    for (int r=0;r<4;r++){
      #pragma unroll
      for (int v=0;v<4;v++){
        int row = bm + r*16 + (lane>>4)*4 + v;
        if (row >= M*X) continue;
        int ge = row / X, gx = row - ge*X;
        size_t o = (size_t)ge*CO*X + (size_t)col*X + gx;
        float xx = acc[r][v];
        if (GATE){
          float p = P[(size_t)ge*PS + POFF + col];
          C[o] = A[o] + xx*p;   // CI==CO => A layout == C layout
        } else {
          if (ACC) xx += (Dacc ? Dacc[o] : C[o]);
          C[o] = xx;
        }
      }
    }
  }
}

// ------------------------- small kernels -------------------------
__global__ void k_sentinel(float* o, int n, float v){
  int i = blockIdx.x*256 + threadIdx.x;
  if (i < n) o[i] = v;
}

__global__ void k_geom(const float* __restrict__ pos, const int* __restrict__ src, const int* __restrict__ dst,
                       float* __restrict__ U, float* __restrict__ Rr, float* __restrict__ SH2b){
  int e = blockIdx.x*256 + threadIdx.x;
  if (e >= NE) return;
  int s = src[e], d = dst[e];
  float vx = pos[s*3+0]-pos[d*3+0];
  float vy = pos[s*3+1]-pos[d*3+1];
  float vz = pos[s*3+2]-pos[d*3+2];
  float r = sqrtf(vx*vx+vy*vy+vz*vz + 1e-12f);
  float ux=vx/r, uy=vy/r, uz=vz/r;
  U[e*3+0]=ux; U[e*3+1]=uy; U[e*3+2]=uz;
  Rr[e]=r;
  SH2b[e*5+0]=SQ15F*ux*uy;
  SH2b[e*5+1]=SQ15F*uy*uz;
  SH2b[e*5+2]=0.5f*SQ5F*(3.0f*uz*uz-1.0f);
  SH2b[e*5+3]=SQ15F*ux*uz;
  SH2b[e*5+4]=0.5f*SQ15F*(ux*ux-uy*uy);
}

__global__ void k_f0init(const int* __restrict__ na, const float* __restrict__ at, float* __restrict__ f0){
  int t = blockIdx.x*256 + threadIdx.x;
  if (t >= NN*128) return;
  int n = t>>7, j = t&127;
  int m = c_amap[na[n]];
  f0[t] = at[m*128+j];
}

// fused post-block: AB normalize + finy residual + bf16 checkpoint
__global__ void k_postblk(const float* __restrict__ x0,const float* __restrict__ x1,const float* __restrict__ x2,
                          float* __restrict__ y0,float* __restrict__ y1,float* __restrict__ y2,
                          const float* __restrict__ S, unsigned short* __restrict__ ck,
                          const float* __restrict__ Pl, const int* __restrict__ dst, float* __restrict__ AB){
  int t = blockIdx.x*256 + threadIdx.x;
  if (t < NE) AB[t] = Pl[t]/(S[dst[t]]+1e-9f);
  if (t >= NN*480) return;
  float v;
  if (t < NN*128){ int n=t>>7; v = x0[t] + y0[t]/(S[n]+1e-9f); y0[t]=v; }
  else if (t < NN*320){ int q=t-NN*128; int n=q/192; v = x1[q] + y1[q]/(S[n]+1e-9f); y1[q]=v; }
  else { int q=t-NN*320; int n=q/160; v = x2[q] + y2[q]/(S[n]+1e-9f); y2[q]=v; }
  ck[t] = f2b(v);
}

// bf16 checkpoint quant
__global__ void k_q3(const float* __restrict__ f0,const float* __restrict__ f1,const float* __restrict__ f2,
                     unsigned short* __restrict__ ck){
  int t = blockIdx.x*256 + threadIdx.x;
  if (t >= NN*480) return;
  float v;
  if (t < NN*128) v = f0[t];
  else if (t < NN*320) v = f1[t-NN*128];
  else v = f2[t-NN*320];
  ck[t] = f2b(v);
}
// dual dequant
__global__ void k_dq3x2(const unsigned short* __restrict__ cka, const unsigned short* __restrict__ ckb,
                        float* __restrict__ a0,float* __restrict__ a1,float* __restrict__ a2,
                        float* __restrict__ b0,float* __restrict__ b1,float* __restrict__ b2){
  int t = blockIdx.x*256 + threadIdx.x;
  if (t >= NN*480) return;
  float va = b2f(cka[t]), vb = b2f(ckb[t]);
  if (t < NN*128){ a0[t]=va; b0[t]=vb; }
  else if (t < NN*320){ int q=t-NN*128; a1[q]=va; b1[q]=vb; }
  else { int q=t-NN*320; a2[q]=va; b2[q]=vb; }
}

// per-graph aggregation; SC strided 352 [sv0|sw0|sw1|sw2]; accumulates S in lanes 480..495
template<bool INIT>
__global__ __launch_bounds__(512) void k_agg(
  float* __restrict__ f0o,float* __restrict__ f1o,float* __restrict__ f2o,
  const float* __restrict__ SC,const float* __restrict__ sv1,const float* __restrict__ sv2,
  const float* __restrict__ g,const float* __restrict__ U,const float* __restrict__ SH2b,
  const float* __restrict__ aArr,const int* __restrict__ keys,const int* __restrict__ dst,
  float* __restrict__ SACC, int c0, int c1)
{
  __shared__ float acc[7680];
  int b = blockIdx.x, lo = b<<4;
  int e0 = lbound(keys, NE, lo), e1 = lbound(keys, NE, lo+16);
  if (e0 < c0) e0 = c0;
  if (e1 > c1) e1 = c1;
  if (e0 >= e1) return;
  for (int i=threadIdx.x;i<7680;i+=512) acc[i]=0.0f;
  __syncthreads();
  const int j = threadIdx.x;
  const float inv = 1.0f/sqrtf(15.57f);
  int cat=3, cc_=0, xx_=0;
  if (j<128){ cat=0; }
  else if (j<320){ cat=1; int t=j-128; cc_=t/3; xx_=t-3*cc_; }
  else if (j<480){ cat=2; int t=j-320; cc_=t/5; xx_=t-5*cc_; }
  float sacc=0.0f;
  for (int e=e0; e<e1; ++e){
    int el = e - c0;
    float a = INIT ? inv : aArr[e];
    int nl = dst[e]&15;
    if (cat==0){
      float m = INIT ? g[el*224+j] : (SC[(size_t)el*352+j]*g[el*224+j] + SC[(size_t)el*352+128+j]);
      acc[nl*480+j] += a*m;
    } else if (cat==1){
      int t=j-128;
      float sh = SQ3F*U[e*3+xx_];
      float m = INIT ? g[el*224+128+cc_]*sh : (sv1[el*192+t]*g[el*224+128+cc_] + SC[(size_t)el*352+256+cc_]*sh);
      acc[nl*480+j] += a*m;
    } else if (cat==2){
      int t=j-320;
      float sh = SH2b[e*5+xx_];
      float m = INIT ? g[el*224+192+cc_]*sh : (sv2[el*160+t]*g[el*224+192+cc_] + SC[(size_t)el*352+320+cc_]*sh);
      acc[nl*480+j] += a*m;
    } else if (!INIT && j<496){
      if (nl==(j-480)) sacc += a;
    }
  }
  __syncthreads();
  for (int i=threadIdx.x;i<7680;i+=512){
    int nl=i/480, jj=i-480*nl, n=lo+nl;
    float v=acc[i];
    if (jj<128) f0o[n*128+jj]+=v;
    else if (jj<320) f1o[n*192+jj-128]+=v;
    else f2o[n*160+jj-320]+=v;
  }
  if (!INIT && j>=480 && j<496) SACC[lo+(j-480)] += sacc;
}

// per-graph scatter of edge grads
__global__ __launch_bounds__(640) void k_scat(
  float* __restrict__ df0, float* __restrict__ df1, float* __restrict__ df2,
  const float* __restrict__ DE0, const float* __restrict__ DZD,
  const float* __restrict__ DE1, const float* __restrict__ DE2,
  const int* __restrict__ src, const int* __restrict__ dst, int c0, int c1)
{
  __shared__ float acc[7680];
  int b=blockIdx.x, lo=b<<4;
  int e0=lbound(dst,NE,lo), e1=lbound(dst,NE,lo+16);
  if (e0 < c0) e0 = c0;
  if (e1 > c1) e1 = c1;
  for (int i=threadIdx.x;i<7680;i+=640) acc[i]=0.0f;
  __syncthreads();
  const int j=threadIdx.x;
  for (int e=e0;e<e1;++e){
    int el=e-c0;
    int sl=(src[e]&15)*480, dl=(dst[e]&15)*480;
    if (j<128) acc[sl+j] += DE0[el*128+j];
    else if (j<256){ int q=j-128; acc[dl+q] += DZD[el*128+q]; }
    else if (j<448){ int q=j-256; acc[sl+128+q] += DE1[el*192+q]; }
    else if (j<608){ int q=j-448; acc[sl+320+q] += DE2[el*160+q]; }
    __syncthreads();
  }
  for (int i=threadIdx.x;i<7680;i+=640){
    int nl=i/480, jj=i-480*nl, n=lo+nl;
    float v=acc[i];
    if (jj<128) df0[n*128+jj]+=v;
    else if (jj<320) df1[n*192+jj-128]+=v;
    else df2[n*160+jj-320]+=v;
  }
}

// SSUM[n] = (FB[n]-FA[n]) . DY[n]; also DI* = DY* (fold the 3 memcpys)
__global__ __launch_bounds__(256) void k_ssum(
  const float* __restrict__ FA0,const float* __restrict__ FA1,const float* __restrict__ FA2,
  const float* __restrict__ FB0,const float* __restrict__ FB1,const float* __restrict__ FB2,
  const float* __restrict__ DY0,const float* __restrict__ DY1,const float* __restrict__ DY2,
  float* __restrict__ SSUM,
  float* __restrict__ DI0o, float* __restrict__ DI1o, float* __restrict__ DI2o)
{
  int n=blockIdx.x*4+(threadIdx.x>>6), lane=threadIdx.x&63;
  if (n>=NN) return;
  float s=0.0f;
  for (int j=lane;j<480;j+=64){
    float d,g;
    if (j<128){ d=FB0[n*128+j]-FA0[n*128+j]; g=DY0[n*128+j]; DI0o[n*128+j]=g; }
    else if (j<320){ int q=j-128; d=FB1[n*192+q]-FA1[n*192+q]; g=DY1[n*192+q]; DI1o[n*192+q]=g; }
    else { int q=j-320; d=FB2[n*160+q]-FA2[n*160+q]; g=DY2[n*160+q]; DI2o[n*160+q]=g; }
    s += d*g;
  }
  s = wred64(s);
  if (lane==0) SSUM[n]=s;
}

// fused backward edge chain: da -> dlam -> dz -> split0/1/2 ; one wave per edge
__global__ __launch_bounds__(256) void k_bedge(
  float* __restrict__ SC, float* __restrict__ SV1, float* __restrict__ SV2,
  const float* __restrict__ g, const float* __restrict__ U, const float* __restrict__ SH2b,
  const float* __restrict__ df0,const float* __restrict__ df1,const float* __restrict__ df2,
  const int* __restrict__ dst, const float* __restrict__ SSUM, const float* __restrict__ wa,
  float* __restrict__ Z, const float* __restrict__ aArr,
  float* __restrict__ DG, float* __restrict__ DSH1, float* __restrict__ DSH2,
  int c0, int cnt)
{
  int w=threadIdx.x>>6, lane=threadIdx.x&63;
  int el=blockIdx.x*4+w;
  if (el>=cnt) return;
  int e=c0+el;
  int d=dst[e];
  float s=0.0f;
  for (int j=lane;j<480;j+=64){
    float m, dfv;
    if (j<128){
      m = SC[(size_t)el*352+j]*g[el*224+j] + SC[(size_t)el*352+128+j];
      dfv = df0[(size_t)d*128+j];
    } else if (j<320){
      int t=j-128, c=t/3, x=t-3*c;
      m = SV1[el*192+t]*g[el*224+128+c] + SC[(size_t)el*352+256+c]*(SQ3F*U[e*3+x]);
      dfv = df1[(size_t)d*192+t];
    } else {
      int t=j-320, c=t/5, x=t-5*c;
      m = SV2[el*160+t]*g[el*224+192+c] + SC[(size_t)el*352+320+c]*SH2b[e*5+x];
      dfv = df2[(size_t)d*160+t];
    }
    s += m*dfv;
  }
  s = wred64(s);
  s = __shfl(s,0,64);
  float a = aArr[e];
  float dlam = a*(s - SSUM[d]);
  if (lane<32){
    float z = Z[(size_t)el*32+lane];
    Z[(size_t)el*32+lane] = dlam*wa[lane]*(1.0f-z*z);
  }
  {
    float* row = SC + (size_t)el*352;
    for (int j=lane;j<128;j+=64){
      float dm = a*df0[(size_t)d*128+j];
      float sv = row[j];
      row[128+j] = dm;
      row[j] = dm*g[el*224+j];
      DG[el*224+j] = dm*sv;
    }
  }
  {
    float dm0=a*df1[(size_t)d*192+lane*3+0];
    float dm1=a*df1[(size_t)d*192+lane*3+1];
    float dm2=a*df1[(size_t)d*192+lane*3+2];
    float sw1o=SC[(size_t)el*352+256+lane];
    float g1=g[el*224+128+lane];
    float c0v=dm0*sw1o, c1v=dm1*sw1o, c2v=dm2*sw1o;
    c0v=wred64(c0v); c1v=wred64(c1v); c2v=wred64(c2v);
    if (lane==0){ DSH1[e*3+0]+=c0v; DSH1[e*3+1]+=c1v; DSH1[e*3+2]+=c2v; }
    float sh0=SQ3F*U[e*3+0], sh1=SQ3F*U[e*3+1], sh2=SQ3F*U[e*3+2];
    SC[(size_t)el*352+256+lane]=dm0*sh0+dm1*sh1+dm2*sh2;
    float sv0o=SV1[el*192+lane*3+0], sv1o=SV1[el*192+lane*3+1], sv2o=SV1[el*192+lane*3+2];
    DG[el*224+128+lane]=dm0*sv0o+dm1*sv1o+dm2*sv2o;
    SV1[el*192+lane*3+0]=dm0*g1; SV1[el*192+lane*3+1]=dm1*g1; SV1[el*192+lane*3+2]=dm2*g1;
  }
  {
    float dm[5]={0,0,0,0,0}, svo[5]={0,0,0,0,0};
    float sw2o=0.0f, g2=0.0f;
    if (lane<32){
      #pragma unroll
      for (int x=0;x<5;x++){ dm[x]=a*df2[(size_t)d*160+lane*5+x]; svo[x]=SV2[el*160+lane*5+x]; }
      sw2o=SC[(size_t)el*352+320+lane]; g2=g[el*224+192+lane];
    }
    float c[5];
    #pragma unroll
    for (int x=0;x<5;x++){ c[x]=dm[x]*sw2o; c[x]=wred64(c[x]); }
    if (lane==0){
      #pragma unroll
      for (int x=0;x<5;x++) DSH2[e*5+x]+=c[x];
    }
    if (lane<32){
      float dsw=0.0f, dg2=0.0f;
      #pragma unroll
      for (int x=0;x<5;x++){ dsw+=dm[x]*SH2b[e*5+x]; dg2+=dm[x]*svo[x]; }
      SC[(size_t)el*352+320+lane]=dsw;
      DG[el*224+192+lane]=dg2;
      #pragma unroll
      for (int x=0;x<5;x++) SV2[el*160+lane*5+x]=dm[x]*g2;
    }
  }
}

// fused gate backward (both gate blocks in one launch)
__global__ void k_gateback2(const float* __restrict__ dfB1, float* __restrict__ V1,
                            const float* __restrict__ dfB2, float* __restrict__ V2,
                            const float* __restrict__ P12, float* __restrict__ DPa){
  int t=blockIdx.x*256+threadIdx.x;
  if (t < NN*64){
    int n=t>>6, d=t&63;
    float p=P12[(size_t)n*96+d];
    float dp=0.0f;
    #pragma unroll
    for (int x=0;x<3;x++){ dp += dfB1[(size_t)t*3+x]*V1[(size_t)t*3+x]; }
    #pragma unroll
    for (int x=0;x<3;x++){ V1[(size_t)t*3+x] = dfB1[(size_t)t*3+x]*p; }
    DPa[(size_t)n*96+d] = dp*p*(1.0f-p);
  } else if (t < NN*96){
    int t2=t-NN*64;
    int n=t2>>5, d=t2&31;
    float p=P12[(size_t)n*96+64+d];
    float dp=0.0f;
    #pragma unroll
    for (int x=0;x<5;x++){ dp += dfB2[(size_t)t2*5+x]*V2[(size_t)t2*5+x]; }
    #pragma unroll
    for (int x=0;x<5;x++){ V2[(size_t)t2*5+x] = dfB2[(size_t)t2*5+x]*p; }
    DPa[(size_t)n*96+64+d] = dp*p*(1.0f-p);
  }
}

__global__ __launch_bounds__(256) void k_dr(const float* __restrict__ DRBF, const float* __restrict__ Rr,
    const float* __restrict__ cen, const float* __restrict__ wid, float* __restrict__ DRa, int c0, int cnt){
  int w=threadIdx.x>>6, lane=threadIdx.x&63;
  int el=blockIdx.x*4+w;
  if (el>=cnt) return;
  int e=c0+el;
  float r=Rr[e], s=0.0f;
  for (int k=lane;k<128;k+=64){
    float c=cen[k], wd=wid[k];
    float t=(r-c)/wd;
    float rb=expf(-0.5f*t*t);
    s += DRBF[el*128+k]*rb*((c-r)/(wd*wd));
  }
  s=wred64(s);
  if (lane==0) DRa[e]+=s;
}

__global__ __launch_bounds__(256) void k_initback(
  const float* __restrict__ df0,const float* __restrict__ df1,const float* __restrict__ df2,
  const int* __restrict__ dst,
  const float* __restrict__ g,const float* __restrict__ U,const float* __restrict__ SH2b,
  float* __restrict__ DG,float* __restrict__ DSH1,float* __restrict__ DSH2, int c0, int cnt)
{
  int w=threadIdx.x>>6, lane=threadIdx.x&63;
  int el=blockIdx.x*4+w;
  if (el>=cnt) return;
  int e=c0+el;
  int d=dst[e];
  const float inv=1.0f/sqrtf(15.57f);
  for (int j=lane;j<128;j+=64) DG[el*224+j]=inv*df0[d*128+j];
  float sh0=SQ3F*U[e*3+0], sh1=SQ3F*U[e*3+1], sh2=SQ3F*U[e*3+2];
  float df10=df1[d*192+lane*3+0], df11=df1[d*192+lane*3+1], df12=df1[d*192+lane*3+2];
  float g1=g[el*224+128+lane];
  DG[el*224+128+lane]=inv*(df10*sh0+df11*sh1+df12*sh2);
  float c0v=g1*df10, c1v=g1*df11, c2v=g1*df12;
  c0v=wred64(c0v); c1v=wred64(c1v); c2v=wred64(c2v);
  if (lane==0){ DSH1[e*3+0]+=inv*c0v; DSH1[e*3+1]+=inv*c1v; DSH1[e*3+2]+=inv*c2v; }
  float cc[5]={0,0,0,0,0};
  if (lane<32){
    float g2=g[el*224+192+lane];
    float dgv=0.0f;
    #pragma unroll
    for (int x=0;x<5;x++){ float dfv=df2[d*160+lane*5+x]; dgv+=dfv*SH2b[e*5+x]; cc[x]=g2*dfv; }
    DG[el*224+192+lane]=inv*dgv;
  }
  #pragma unroll
  for (int x=0;x<5;x++) cc[x]=wred64(cc[x]);
  if (lane==0){
    #pragma unroll
    for (int x=0;x<5;x++) DSH2[e*5+x]+=inv*cc[x];
  }
}

__global__ void k_geoback(const float* __restrict__ DRa, const float* __restrict__ DSH1, const float* __restrict__ DSH2,
                          const float* __restrict__ U, const float* __restrict__ Rr,
                          const int* __restrict__ src, const int* __restrict__ dst,
                          float* __restrict__ DPOS){
  int e=blockIdx.x*256+threadIdx.x;
  if (e>=NE) return;
  float ux=U[e*3+0], uy=U[e*3+1], uz=U[e*3+2];
  float r=Rr[e];
  float dux=SQ3F*DSH1[e*3+0], duy=SQ3F*DSH1[e*3+1], duz=SQ3F*DSH1[e*3+2];
  float d0=DSH2[e*5+0],d1=DSH2[e*5+1],d2=DSH2[e*5+2],d3=DSH2[e*5+3],d4=DSH2[e*5+4];
  dux += SQ15F*(uy*d0+uz*d3+ux*d4);
  duy += SQ15F*(ux*d0+uz*d1-uy*d4);
  duz += SQ15F*(uy*d1+ux*d3)+3.0f*SQ5F*uz*d2;
  float dr=DRa[e];
  float dot=dux*ux+duy*uy+duz*uz;
  float dvx=(dux-dot*ux)/r+dr*ux;
  float dvy=(duy-dot*uy)/r+dr*uy;
  float dvz=(duz-dot*uz)/r+dr*uz;
  int s=src[e], d=dst[e];
  atomicAdd(&DPOS[s*3+0],dvx); atomicAdd(&DPOS[s*3+1],dvy); atomicAdd(&DPOS[s*3+2],dvz);
  atomicAdd(&DPOS[d*3+0],-dvx); atomicAdd(&DPOS[d*3+1],-dvy); atomicAdd(&DPOS[d*3+2],-dvz);
}

__global__ void k_forces(const float* __restrict__ DPOS, float* __restrict__ o){
  int i=blockIdx.x*256+threadIdx.x;
  if (i<NN*3) o[i]=-DPOS[i];
}

// per-node LN + head forward + backward seeds; single wave per node
__global__ __launch_bounds__(64) void k_lnhead(
  const float* __restrict__ f0,const float* __restrict__ f1,const float* __restrict__ f2,
  const float* __restrict__ lng,const float* __restrict__ lnb,
  const float* __restrict__ W0,const float* __restrict__ hout,
  float* __restrict__ EN, float* __restrict__ df0,float* __restrict__ df1,float* __restrict__ df2)
{
  __shared__ float xh[480];
  __shared__ float fl[128];
  __shared__ float dyv[128];
  __shared__ float dxh[128];
  int n=blockIdx.x, lane=threadIdx.x;
  const float c0=1.0f/sqrtf(18.03f);
  for (int i=lane;i<480;i+=64){
    float v=(i<128)? f0[n*128+i] : (i<320)? f1[n*192+(i-128)] : f2[n*160+(i-320)];
    xh[i]=v;
  }
  __syncthreads();
  float s1=0.0f,s2=0.0f;
  for (int i=lane;i<480;i+=64){ float v=xh[i]; s1+=v; s2+=v*v; }
  s1=wred64(s1); s2=wred64(s2);
  float mu=__shfl(s1,0,64)*(1.0f/480.0f);
  float var=__shfl(s2,0,64)*(1.0f/480.0f)-mu*mu;
  float rstd=rsqrtf(var+1e-5f);
  for (int i=lane;i<480;i+=64) xh[i]=(xh[i]-mu)*rstd;
  __syncthreads();
  for (int k=lane;k<128;k+=64) fl[k]=xh[k]*lng[k]+lnb[k];
  __syncthreads();
  float y0=0.0f,y1=0.0f;
  for (int k=0;k<128;k++){ float f=fl[k]; y0+=f*W0[k*128+lane]; y1+=f*W0[k*128+lane+64]; }
  float e = siluf(y0)*hout[lane] + siluf(y1)*hout[lane+64];
  e=wred64(e);
  if (lane==0) EN[n]=e*c0;
  dyv[lane]=c0*hout[lane]*dsiluf(y0);
  dyv[lane+64]=c0*hout[lane+64]*dsiluf(y1);
  __syncthreads();
  float d0=0.0f,d1=0.0f;
  for (int j=0;j<128;j++){ float dv=dyv[j]; d0+=dv*W0[lane*128+j]; d1+=dv*W0[(lane+64)*128+j]; }
  dxh[lane]=d0*lng[lane];
  dxh[lane+64]=d1*lng[lane+64];
  __syncthreads();
  float s3=dxh[lane]+dxh[lane+64];
  float s4=dxh[lane]*xh[lane]+dxh[lane+64]*xh[lane+64];
  s3=wred64(s3); s4=wred64(s4);
  float m1=__shfl(s3,0,64)*(1.0f/480.0f);
  float m2=__shfl(s4,0,64)*(1.0f/480.0f);
  for (int i=lane;i<480;i+=64){
    float dv=rstd*(((i<128)?dxh[i]:0.0f)-m1-xh[i]*m2);
    if (i<128) df0[n*128+i]=dv;
    else if (i<320) df1[n*192+(i-128)]=dv;
    else df2[n*160+(i-320)]=dv;
  }
}

__global__ void k_esum(const float* __restrict__ EN, float* __restrict__ out){
  int b=blockIdx.x*64+threadIdx.x;
  if (b<NG){
    float s=0.0f;
    for (int k=0;k<16;k++) s+=EN[b*16+k];
    out[b]=s;
  }
}

#define MG(MT,TB,ACC,ACT,GA,SP,AR,DM,PO, A,IDX,B,C,M,Nd,K, CEN,WID,DMp,POp,DAp) \
  k_mgemm<MT,TB,ACC,ACT,GA,SP,AR,DM,PO><<<dim3((unsigned)(((M)+(MT)-1)/(MT)),(unsigned)(((Nd)+63)/64)),dim3(256),0,stream>>>((A),(IDX),(B),(C),(M),(Nd),(K),(CEN),(WID),(DMp),(POp),(DAp))
#define MGEMM(MT,TB,ACC,ACT,GA, A,IDX,B,C,M,Nd,K) MG(MT,TB,ACC,ACT,GA,false,false,false,false, A,IDX,B,C,M,Nd,K, nullptr,nullptr,nullptr,nullptr,nullptr)
#define MGEMMD(MT,TB,ACC,ACT,GA, A,IDX,B,C,M,Nd,K,DA) MG(MT,TB,ACC,ACT,GA,false,false,false,false, A,IDX,B,C,M,Nd,K, nullptr,nullptr,nullptr,nullptr,DA)
#define MGEMM3(MT,TB,ACC,ACT,GA, A,IDX,B,C,M,Nd,K) MG(MT,TB,ACC,ACT,GA,true,false,false,false, A,IDX,B,C,M,Nd,K, nullptr,nullptr,nullptr,nullptr,nullptr)
#define MEINS(CI,CO,X,TB,ACC,GA, A,IDX,Wt,C,M) \
  k_meinsum<CI,CO,X,TB,ACC,GA,false,false><<<dim3((unsigned)(((M)*(X)+63)/64)),dim3(256),0,stream>>>((A),(IDX),(Wt),(C),(M),nullptr,0,0,nullptr)
#define MEINSD(CI,CO,X,TB,ACC,GA, A,IDX,Wt,C,M,DA) \
  k_meinsum<CI,CO,X,TB,ACC,GA,false,false><<<dim3((unsigned)(((M)*(X)+63)/64)),dim3(256),0,stream>>>((A),(IDX),(Wt),(C),(M),nullptr,0,0,(DA))
#define MEINS3(CI,CO,X,TB,ACC,GA, A,IDX,Wt,C,M) \
  k_meinsum<CI,CO,X,TB,ACC,GA,true,false><<<dim3((unsigned)(((M)*(X)+63)/64)),dim3(256),0,stream>>>((A),(IDX),(Wt),(C),(M),nullptr,0,0,nullptr)
#define MEINSG(CI,CO,X,SP, A,Wt,C,M, Pp,POFF) \
  k_meinsum<CI,CO,X,false,false,false,SP,true><<<dim3((unsigned)(((M)*(X)+63)/64)),dim3(256),0,stream>>>((A),nullptr,(Wt),(C),(M),(Pp),96,(POFF),nullptr)
#define MLP2(SP,PR, RRp,W1p,W2p,H2p,P1p,P2p,M) \
  k_mlp2<SP,PR><<<dim3((unsigned)(((M)+63)/64)),dim3(256),0,stream>>>((RRp),rbfc,rbfw,(W1p),(W2p),(H2p),(P1p),(P2p),(M))
#define BMLP2(AC, DGp,W3p,W2p,HPp,P2p,P1p,H1p,M) \
  k_bmlp2<AC><<<dim3((unsigned)(((M)+63)/64)),dim3(256),0,stream>>>((DGp),(W3p),(W2p),(HPp),(P2p),(P1p),(H1p),(M))
#define G256(n) dim3((unsigned)(((n)+255)/256)),dim3(256),0,stream
#define GW4(n) dim3((unsigned)(((n)+3)/4)),dim3(256),0,stream

extern "C" void kernel_launch(void* const* d_in, const int* in_sizes, int n_in,
                              void* d_out, int out_size, void* d_ws, size_t ws_size,
                              hipStream_t stream)
{
  const float* pos =(const float*)d_in[0];
  const float* atab=(const float*)d_in[1];
  const float* rbfc=(const float*)d_in[2];
  const float* rbfw=(const float*)d_in[3];
  const float* degW1=(const float*)d_in[4];
  const float* degW2=(const float*)d_in[5];
  const float* degW3=(const float*)d_in[6];
  const float* Wv0=(const float*)d_in[7];
  const float* Wv1=(const float*)d_in[8];
  const float* Wv2=(const float*)d_in[9];
  const float* Ws0=(const float*)d_in[10];
  const float* Ws1=(const float*)d_in[11];
  const float* Ws2=(const float*)d_in[12];
  const float* rW1=(const float*)d_in[13];
  const float* rW2=(const float*)d_in[14];
  const float* rW3=(const float*)d_in[15];
  const float* WaS=(const float*)d_in[16];
  const float* WaD=(const float*)d_in[17];
  const float* WaE=(const float*)d_in[18];
  const float* wab=(const float*)d_in[19];
  const float* ff1=(const float*)d_in[20];
  const float* ff2=(const float*)d_in[21];
  const float* fg1=(const float*)d_in[22];
  const float* fg2=(const float*)d_in[23];
  const float* fW1=(const float*)d_in[24];
  const float* fW2=(const float*)d_in[25];
  const float* lng=(const float*)d_in[26];
  const float* lnb=(const float*)d_in[27];
  const float* W0h=(const float*)d_in[28];
  const float* hout=(const float*)d_in[29];
  const int* natom=(const int*)d_in[30];
  const int* esrc=(const int*)d_in[31];
  const int* edst=(const int*)d_in[32];

  float* Wp=(float*)d_ws;
  size_t off=0;
  auto al=[&](size_t n)->float*{ float* q=Wp+off; off+=n; return q; };

  const size_t SLOT = (size_t)NN*480;
  unsigned short* CKB = (unsigned short*)al((9*SLOT+1)/2);
  float* FA0=al((size_t)NN*128); float* FA1=al((size_t)NN*192); float* FA2=al((size_t)NN*160);
  float* FB0=al((size_t)NN*128); float* FB1=al((size_t)NN*192); float* FB2=al((size_t)NN*160);
  float* DI0=al((size_t)NN*128); float* DI1=al((size_t)NN*192); float* DI2=al((size_t)NN*160);
  float* DY0=al((size_t)NN*128); float* DY1=al((size_t)NN*192); float* DY2=al((size_t)NN*160);
  float* U=al((size_t)NE*3); float* Rr=al(NE); float* SH2b=al((size_t)NE*5);
  float* ABLK=al(8ULL*NE); float* LAM=al(NE);
  float* SSUM=al(NN); float* ENODE=al(NN); float* SACC=al(NN);
  float* DRr=al(NE); float* DSH1=al((size_t)NE*3); float* DSH2=al((size_t)NE*5);
  float* DPOS=al((size_t)NN*3);
  float* WCATF=al(8ULL*128*352);
  float* WCATZ=al(8ULL*320*32);
  float* WCATG=al(8ULL*128*96);
  int* ROWS =(int*)al(NN+1);
  int* CNT  =(int*)al(NN);
  int* POSB =(int*)al(NN);
  int* PERMB=(int*)al(NE);
  int* ESRC2=(int*)al(NE);
  int* EDST2=(int*)al(NE);

  // ---- UNION region: per-phase chunk layouts + node-phase buffers (all time-disjoint) ----
  const size_t UNI = 28800000;
  float* UN = al(UNI);
  float* TBc=UN;
  float* DTc=TBc+(size_t)NNC*512;
  float* P12=DTc+(size_t)NNC*512;
  float* V1 =P12+(size_t)NN*96;
  float* V2 =V1 +(size_t)NN*192;
  float* DPb=V2 +(size_t)NN*160;
  float* F0N=DPb+(size_t)NN*96;

  float* outE=(float*)d_out;
  float* outF=outE+NG;

  if (off*sizeof(float) > ws_size){
    k_sentinel<<<G256(out_size)>>>(outE, out_size, (float)ws_size);
    return;
  }

  // ---------------- sort edges by dst ----------------
  (void)hipMemsetAsync(CNT,0,NN*sizeof(int),stream);
  k_hist<<<G256(NE)>>>(edst,CNT,NE);
  k_scan0<<<dim3(1),dim3(256),0,stream>>>(CNT,ROWS);
  (void)hipMemcpyAsync(POSB,ROWS,NN*sizeof(int),hipMemcpyDeviceToDevice,stream);
  k_fillperm<<<G256(NE)>>>(edst,POSB,PERMB,NE);
  k_mkedge<<<G256(NE)>>>(PERMB,esrc,edst,ESRC2,EDST2);
  k_wcat<<<G256(8*128*352)>>>(Wv0,Ws0,Ws1,Ws2,WCATF);
  k_wcatz<<<G256(8*320*32)>>>(WaS,WaD,WaE,WCATZ);
  k_wcatg<<<G256(8*128*96)>>>(fg1,fg2,WCATG);

  // ---------------- setup ----------------
  k_geom<<<G256(NE)>>>(pos,ESRC2,EDST2,U,Rr,SH2b);
  k_f0init<<<G256(NN*128)>>>(natom,atab,FA0);
  (void)hipMemsetAsync(FA1,0,(size_t)NN*352*4,stream);   // FA1+FA2 contiguous
  (void)hipMemsetAsync(DRr,0,(size_t)NE*4,stream);
  (void)hipMemsetAsync(DSH1,0,(size_t)NE*3*4,stream);
  (void)hipMemsetAsync(DSH2,0,(size_t)NE*5*4,stream);
  (void)hipMemsetAsync(DPOS,0,(size_t)NN*3*4,stream);

  // degree embedding (CHIF chunks) -> FA  [split-bf16 + fused RBF MLP]
  {
    float* H1=UN; float* H2=H1+(size_t)CHIF*64; float* Gc=H2+(size_t)CHIF*64;
    (void)H1;
    for (int cc=0;cc<NIF;cc++){
      int c0e=cc*CHIF, cnt=(c0e+CHIF<=NE)?CHIF:(NE-c0e);
      MLP2(true,false, Rr+c0e, degW1, degW2, H2, nullptr, nullptr, cnt);
      MGEMM3(64,false,false,0,false, H2,nullptr,degW3,Gc, cnt,224,64);
      k_agg<true><<<dim3(NG),dim3(512),0,stream>>>(FA0,FA1,FA2,
        nullptr,nullptr,nullptr, Gc,U,SH2b, nullptr, EDST2,EDST2, nullptr, c0e,c0e+cnt);
    }
  }
  k_q3<<<G256(NN*480)>>>(FA0,FA1,FA2, CKB);

  // forward feature buffers: f0 ping-pongs, f1/f2 stay
  float *c0_=FA0,*c1_=FA1,*c2_=FA2, *n0_=FB0,*n1_=FB1,*n2_=FB2;

  // ---------------- forward blocks [split-bf16], CHF chunks ----------------
  {
    float* H1  =UN;
    float* H2  =H1  +(size_t)CHF*64;
    float* Gc  =H2  +(size_t)CHF*64;
    float* SCAT=Gc  +(size_t)CHF*224;
    float* SV1 =SCAT+(size_t)CHF*352;
    float* SV2 =SV1 +(size_t)CHF*192;
    float* Zc  =SV2 +(size_t)CHF*160;
    (void)H1;
    for (int i=0;i<8;i++){
      const float* Wv1i=Wv1+(size_t)i*4096; const float* Wv2i=Wv2+(size_t)i*1024;
      const float* rW1i=rW1+(size_t)i*8192; const float* rW2i=rW2+(size_t)i*4096; const float* rW3i=rW3+(size_t)i*14336;
      const float* WZi=WCATZ+(size_t)i*10240;
      const float* ff1i=ff1+(size_t)i*65536; const float* ff2i=ff2+(size_t)i*65536;
      const float* fgCi=WCATG+(size_t)i*12288;
      const float* fW1i=fW1+(size_t)i*4096; const float* fW2i=fW2+(size_t)i*1024;
      const float* WCi=WCATF+(size_t)i*45056;
      float* AB=ABLK+(size_t)i*NE;

      (void)hipMemsetAsync(SACC,0,(size_t)NN*4,stream);
      (void)hipMemsetAsync(n0_,0,(size_t)NN*128*4,stream);
      (void)hipMemsetAsync(n1_,0,(size_t)NN*352*4,stream);   // n1_,n2_ = FB1,FB2 contiguous
      for (int cc=0;cc<NF;cc++){
        int c0e=cc*CHF, cnt=(c0e+CHF<=NE)?CHF:(NE-c0e);
        MLP2(true,false, Rr+c0e, rW1i, rW2i, H2, nullptr, nullptr, cnt);
        MGEMM3(64,false,false,0,false, H2,nullptr,rW3i,Gc, cnt,224,64);
        k_zgemm<true,true><<<dim3((unsigned)((cnt+63)/64)),dim3(256),0,stream>>>(
            c0_, ESRC2+c0e, EDST2+c0e, H2, WZi, wab+(size_t)i*32, Zc, LAM+c0e, cnt);
        MGEMM3(64,false,false,0,true, c0_,ESRC2+c0e,WCi,SCAT, cnt,352,128);
        MEINS3(64,64,3,false,false,true, c1_,ESRC2+c0e,Wv1i,SV1, cnt);
        MEINS3(32,32,5,false,false,true, c2_,ESRC2+c0e,Wv2i,SV2, cnt);
        k_agg<false><<<dim3(NG),dim3(512),0,stream>>>(n0_,n1_,n2_,
          SCAT,SV1,SV2, Gc,U,SH2b, LAM, EDST2,EDST2, SACC, c0e,c0e+cnt);
      }
      k_postblk<<<G256(NN*480)>>>(c0_,c1_,c2_, n0_,n1_,n2_, SACC, CKB+(size_t)(i+1)*SLOT, LAM, EDST2, AB);
      for (int nc=0;nc<NN/NNC;nc++){
        MGEMM3(64,false,false,1,false, n0_+(size_t)nc*NNC*128,nullptr,ff1i,TBc, NNC,512,128);
        MGEMM3(64,false,true, 0,false, TBc,nullptr,ff2i, n0_+(size_t)nc*NNC*128, NNC,128,512);
      }
      MGEMM3(64,false,false,3,false, n0_,nullptr,fgCi,P12, NN,96,128);
      MEINSG(64,64,3,true, n1_,fW1i,c1_, NN, P12, 0);   // c1_ = n1_ + V1*P(gate1)
      MEINSG(32,32,5,true, n2_,fW2i,c2_, NN, P12, 64);  // c2_ = n2_ + V2*P(gate2)
      float* t;
      t=c0_;c0_=n0_;n0_=t;   // only f0 ping-pongs
    }
  }

  // ---------------- head ----------------
  k_lnhead<<<dim3(NN),dim3(64),0,stream>>>(c0_,c1_,c2_, lng,lnb,W0h,hout, ENODE, DI0,DI1,DI2);
  k_esum<<<dim3(8),dim3(64),0,stream>>>(ENODE,outE);

  // ---------------- backward blocks [plain bf16 MFMA, fused epilogues], CHB chunks ----------------
  {
    float* PRE1=UN;
    float* PRE2=PRE1+(size_t)CHB*64;
    float* H1  =PRE2+(size_t)CHB*64;
    float* H2  =H1  +(size_t)CHB*64;
    float* Gc  =H2  +(size_t)CHB*64;
    float* DGc =Gc  +(size_t)CHB*224;
    float* SCAT=DGc +(size_t)CHB*224;
    float* SV1 =SCAT+(size_t)CHB*352;
    float* SV2 =SV1 +(size_t)CHB*192;
    float* Zc  =SV2 +(size_t)CHB*160;
    float* DE0 =PRE1;   // alias: PRE1+PRE2 (128/edge) dead after rW backward chain
    float* RBFc=DGc;    // alias: DGc dead after rW3^T read
    float* DZD =Gc;     // alias: Gc dead after k_bedge
    for (int i=7;i>=0;--i){
      const float* Wv1i=Wv1+(size_t)i*4096; const float* Wv2i=Wv2+(size_t)i*1024;
      const float* rW1i=rW1+(size_t)i*8192; const float* rW2i=rW2+(size_t)i*4096; const float* rW3i=rW3+(size_t)i*14336;
      const float* WZi=WCATZ+(size_t)i*10240;
      const float* WaSi=WaS+(size_t)i*4096; const float* WaDi=WaD+(size_t)i*4096; const float* WaEi=WaE+(size_t)i*2048;
      const float* ff1i=ff1+(size_t)i*65536; const float* ff2i=ff2+(size_t)i*65536;
      const float* fgCi=WCATG+(size_t)i*12288;
      const float* fW1i=fW1+(size_t)i*4096; const float* fW2i=fW2+(size_t)i*1024;
      const float* WCi=WCATF+(size_t)i*45056;
      const float* AB=ABLK+(size_t)i*NE;
      float *fa1=FA1, *fa2=FA2, *dy1=DY1, *dy2=DY2;

      k_dq3x2<<<G256(NN*480)>>>(CKB+(size_t)i*SLOT, CKB+(size_t)(i+1)*SLOT, FA0,FA1,FA2, FB0,FB1,FB2);
      if (i>0){
        const float* pf1=ff1+(size_t)(i-1)*65536; const float* pf2=ff2+(size_t)(i-1)*65536;
        const float* pgC=WCATG+(size_t)(i-1)*12288;
        const float* pW1=fW1+(size_t)(i-1)*4096; const float* pW2=fW2+(size_t)(i-1)*1024;
        for (int nc=0;nc<NN/NNC;nc++){
          MGEMM(64,false,false,1,false, FA0+(size_t)nc*NNC*128,nullptr,pf1,TBc, NNC,512,128);
          MGEMM(64,false,true, 0,false, TBc,nullptr,pf2, FA0+(size_t)nc*NNC*128, NNC,128,512);
        }
        MGEMM(64,false,false,3,false, FA0,nullptr,pgC,P12, NN,96,128);
        MEINSG(64,64,3,false, FA1,pW1,DY1, NN, P12, 0);   // DY1 = FA1 + V*P
        MEINSG(32,32,5,false, FA2,pW2,DY2, NN, P12, 64);
        fa1=DY1; dy1=FA1; fa2=DY2; dy2=FA2;               // swap roles
      }
      for (int nc=0;nc<NN/NNC;nc++){
        MGEMM(64,false,false,1,false, FB0+(size_t)nc*NNC*128,nullptr,ff1i,TBc, NNC,512,128);
        MGEMMD(64,false,true, 0,false, TBc,nullptr,ff2i, F0N+(size_t)nc*NNC*128, NNC,128,512, FB0+(size_t)nc*NNC*128);
      }
      MGEMM(64,false,false,3,false, F0N,nullptr,fgCi,P12, NN,96,128);
      MEINS(64,64,3,false,false,false, FB1,nullptr,fW1i,V1, NN);
      MEINS(32,32,5,false,false,false, FB2,nullptr,fW2i,V2, NN);
      k_gateback2<<<G256(NN*96)>>>(DI1,V1,DI2,V2,P12,DPb);
      MGEMM(64,true,true,0,false, DPb,nullptr,fgCi,DI0, NN,128,96);
      MEINSD(64,64,3,true,true,false, V1,nullptr,fW1i,dy1, NN, DI1);
      MEINSD(32,32,5,true,true,false, V2,nullptr,fW2i,dy2, NN, DI2);
      for (int nc=0;nc<NN/NNC;nc++){
        MGEMM(64,false,false,0,false, FB0+(size_t)nc*NNC*128,nullptr,ff1i,TBc, NNC,512,128);
        MG(64,true,false,0,false, false,false,true,false, DI0+(size_t)nc*NNC*128,nullptr,ff2i,DTc, NNC,512,128, nullptr,nullptr,TBc,nullptr,nullptr);
        MGEMMD(64,true,true,0,false, DTc,nullptr,ff1i, DY0+(size_t)nc*NNC*128, NNC,128,512, DI0+(size_t)nc*NNC*128);
      }
      k_ssum<<<dim3(NN/4),dim3(256),0,stream>>>(FA0,fa1,fa2,FB0,FB1,FB2,DY0,dy1,dy2,SSUM, DI0,DI1,DI2);
      for (int cc=0;cc<NB;cc++){
        int c0e=cc*CHB, cnt=(c0e+CHB<=NE)?CHB:(NE-c0e);
        MLP2(false,true, Rr+c0e, rW1i, rW2i, H2, PRE1, PRE2, cnt);
        MGEMM(64,false,false,0,false, H2,nullptr,rW3i,Gc, cnt,224,64);
        k_zgemm<false,false><<<dim3((unsigned)((cnt+63)/64)),dim3(256),0,stream>>>(
            FA0, ESRC2+c0e, EDST2+c0e, H2, WZi, nullptr, Zc, nullptr, cnt);
        MGEMM(64,false,false,0,true, FA0,ESRC2+c0e,WCi,SCAT, cnt,352,128);
        MEINS(64,64,3,false,false,true, fa1,ESRC2+c0e,Wv1i,SV1, cnt);
        MEINS(32,32,5,false,false,true, fa2,ESRC2+c0e,Wv2i,SV2, cnt);
        k_bedge<<<GW4(cnt)>>>(SCAT,SV1,SV2, Gc,U,SH2b, DY0,dy1,dy2, EDST2, SSUM,
                              wab+(size_t)i*32, Zc, AB, DGc, DSH1, DSH2, c0e, cnt);
        // rW backward chain: WaE^T partial, then fused (rW3^T+dsilu)->(rW2^T+dsilu) ...
        MGEMM(64,true,false,0,false, Zc,nullptr,WaEi,H2, cnt,64,32);
        BMLP2(true, DGc, rW3i, rW2i, H2, PRE2, PRE1, H1, cnt);
        MGEMM(64,true,false,0,false, H1,nullptr,rW1i,RBFc, cnt,128,64);
        k_dr<<<GW4(cnt)>>>(RBFc,Rr,rbfc,rbfw,DRr, c0e,cnt);
        // ... then edge-grad group into freed regions
        MGEMM(64,true,false,0,false, SCAT,nullptr,WCi,DE0, cnt,128,352);
        MGEMM(64,true,true, 0,false, Zc,nullptr,WaSi,DE0, cnt,128,32);
        MGEMM(64,true,false,0,false, Zc,nullptr,WaDi,DZD, cnt,128,32);
        MEINS(64,64,3,true,false,false, SV1,nullptr,Wv1i,SV1, cnt);
        MEINS(32,32,5,true,false,false, SV2,nullptr,Wv2i,SV2, cnt);
        k_scat<<<dim3(NG),dim3(640),0,stream>>>(DI0,DI1,DI2, DE0,DZD,SV1,SV2, ESRC2,EDST2, c0e,c0e+cnt);
      }
    }
  }

  // ---------------- initial embedding backward [fused], CHIB chunks ----------------
  {
    float* PRE1=UN;
    float* PRE2=PRE1+(size_t)CHIB*64;
    float* H1  =PRE2+(size_t)CHIB*64;
    float* H2  =H1  +(size_t)CHIB*64;
    float* Gc  =H2  +(size_t)CHIB*64;
    float* DGc =Gc  +(size_t)CHIB*224;
    float* RBFc=DGc +(size_t)CHIB*224;
    (void)H1;
    for (int cc=0;cc<NIB;cc++){
      int c0e=cc*CHIB, cnt=(c0e+CHIB<=NE)?CHIB:(NE-c0e);
      MLP2(false,true, Rr+c0e, degW1, degW2, H2, PRE1, PRE2, cnt);
      MGEMM(64,false,false,0,false, H2,nullptr,degW3,Gc, cnt,224,64);
      k_initback<<<GW4(cnt)>>>(DI0,DI1,DI2,EDST2,Gc,U,SH2b,DGc,DSH1,DSH2, c0e,cnt);
      BMLP2(false, DGc, degW3, degW2, nullptr, PRE2, PRE1, H1, cnt);
      MGEMM(64,true,false,0,false, H1,nullptr,degW1,RBFc, cnt,128,64);
      k_dr<<<GW4(cnt)>>>(RBFc,Rr,rbfc,rbfw,DRr, c0e,cnt);
    }
  }

  // ---------------- geometry backward + outputs ----------------
  k_geoback<<<G256(NE)>>>(DRr,DSH1,DSH2,U,Rr,ESRC2,EDST2,DPOS);
  k_forces<<<G256(NN*3)>>>(DPOS,outF);
  (void)in_sizes; (void)n_in; (void)out_size;
}

// Round 13
// 30445.633 us; speedup vs baseline: 1.0284x; 1.0284x over previous
//
#include <hip/hip_runtime.h>
#include <string.h>
#include <math.h>

#define NE 100000
#define NN 8192
#define NG 512
#define CHF 25000
#define NF 4
#define CHB 20000
#define NB 5
#define CHIF 50000
#define NIF 2
#define CHIB 34000
#define NIB 3
#define NNC 8192

#define SQ3F  1.7320508075688772f
#define SQ5F  2.23606797749979f
#define SQ15F 3.872983346207417f

__constant__ int c_amap[10] = {-1,0,-1,-1,-1,-1,1,2,3,4};

typedef __attribute__((ext_vector_type(4))) float f32x4;
typedef __attribute__((ext_vector_type(8))) short bf16x8;

__device__ __forceinline__ float sigf(float x){ return 1.0f/(1.0f+expf(-x)); }
__device__ __forceinline__ float siluf(float x){ return x*sigf(x); }
__device__ __forceinline__ float dsiluf(float x){ float s=sigf(x); return s*(1.0f + x*(1.0f-s)); }

__device__ __forceinline__ float wred64(float v){
  #pragma unroll
  for (int o=32;o>0;o>>=1) v += __shfl_down(v,o,64);
  return v;
}
__device__ __forceinline__ int lbound(const int* a, int n, int v){
  int lo=0, hi=n;
  while (lo<hi){ int m=(lo+hi)>>1; if (a[m]<v) lo=m+1; else hi=m; }
  return lo;
}
__device__ __forceinline__ unsigned short f2b(float x){
  unsigned u=__float_as_uint(x);
  unsigned r=(u + 0x7fffu + ((u>>16)&1u))>>16;
  return (unsigned short)r;
}
__device__ __forceinline__ float b2f(unsigned short b){
  return __uint_as_float(((unsigned)b)<<16);
}

// ---------------- edge sort by dst (counting sort) ----------------
__global__ void k_hist(const int* keys, int* hist, int n){
  int i = blockIdx.x*256 + threadIdx.x;
  if (i < n) atomicAdd(&hist[keys[i]], 1);
}
__global__ __launch_bounds__(256) void k_scan0(const int* hist, int* rows){
  __shared__ int part[256];
  int t = threadIdx.x;
  int base = t*32;
  int loc[32];
  int s = 0;
  #pragma unroll
  for (int i=0;i<32;i++){ loc[i]=s; s+=hist[base+i]; }
  part[t]=s;
  __syncthreads();
  int pre=0;
  for (int i=0;i<t;i++) pre+=part[i];
  #pragma unroll
  for (int i=0;i<32;i++) rows[base+i]=pre+loc[i];
  if (t==255) rows[NN]=pre+s;
}
__global__ void k_fillperm(const int* keys, int* cursor, int* perm, int n){
  int i = blockIdx.x*256 + threadIdx.x;
  if (i < n){
    int slot = atomicAdd(&cursor[keys[i]], 1);
    perm[slot] = i;
  }
}
__global__ void k_mkedge(const int* perm, const int* src, const int* dst, int* src2, int* dst2){
  int k = blockIdx.x*256 + threadIdx.x;
  if (k < NE){ int e = perm[k]; src2[k] = src[e]; dst2[k] = dst[e]; }
}

// weight concat: WCATF[i][k][0:352] = [Wv0 | Ws0 | Ws1 | Ws2]
__global__ void k_wcat(const float* Wv0,const float* Ws0,const float* Ws1,const float* Ws2, float* W){
  int t = blockIdx.x*256 + threadIdx.x;
  if (t >= 8*128*352) return;
  int i = t/45056, r = t - i*45056;
  int k = r/352, n = r - k*352;
  float v;
  if (n < 128) v = Wv0[(size_t)i*16384 + k*128 + n];
  else if (n < 256) v = Ws0[(size_t)i*16384 + k*128 + (n-128)];
  else if (n < 320) v = Ws1[(size_t)i*8192 + k*64 + (n-256)];
  else v = Ws2[(size_t)i*4096 + k*32 + (n-320)];
  W[t] = v;
}
// attention weight concat: WCATZ[i][k][0:32], k in [0,320) = [WaS ; WaD ; WaE]
__global__ void k_wcatz(const float* WaS,const float* WaD,const float* WaE, float* W){
  int t = blockIdx.x*256 + threadIdx.x;
  if (t >= 8*320*32) return;
  int i = t/10240, r = t - i*10240;
  int k = r/32, c = r - k*32;
  float v;
  if (k < 128) v = WaS[(size_t)i*4096 + k*32 + c];
  else if (k < 256) v = WaD[(size_t)i*4096 + (k-128)*32 + c];
  else v = WaE[(size_t)i*2048 + (k-256)*32 + c];
  W[t] = v;
}
// gate weight concat: WCATG[i][k][0:96] = [fg1 | fg2]
__global__ void k_wcatg(const float* fg1,const float* fg2, float* W){
  int t = blockIdx.x*256 + threadIdx.x;
  if (t >= 8*128*96) return;
  int i = t/12288, r = t - i*12288;
  int k = r/96, c = r - k*96;
  float v;
  if (c < 64) v = fg1[(size_t)i*8192 + k*64 + c];
  else v = fg2[(size_t)i*4096 + k*32 + (c-64)];
  W[t] = v;
}

// --- bf16 MFMA GEMM; MT = M-tile; SPLIT=3-term split-bf16; ARBF=A computed as RBF(Rr row);
//     DMUL=epilogue *dsilu(dm); PREOUT=write pre-activation to pre[]; Dacc: accumulator source (else C) ---
template<int MT, bool TB, bool ACC, int ACT, bool GATHER, bool SPLIT, bool ARBF, bool DMUL, bool PREOUT>
__global__ __launch_bounds__(256) void k_mgemm(
    const float* __restrict__ A, const int* __restrict__ idx,
    const float* __restrict__ B, float* __restrict__ C,
    int M, int Nd, int K,
    const float* __restrict__ cen, const float* __restrict__ wid,
    const float* __restrict__ dm, float* __restrict__ pre, const float* __restrict__ Dacc)
{
  constexpr int TPR = 256/MT;     // threads per A-row
  constexpr int EPT = 32/TPR;     // elems per thread (A staging)
  constexpr int RT  = MT/16;      // MFMA row-tiles
  __shared__ unsigned short Asb[(SPLIT?2:1)*MT*40];
  __shared__ unsigned short Btb[(SPLIT?2:1)*2560];
  const int bm = blockIdx.x*MT, bn = blockIdx.y*64;
  const int tid = threadIdx.x;
  const int wave = tid>>6, lane = tid&63;
  const int arow_s = tid / TPR, aoff = (tid % TPR) * EPT;
  const int bsrow = tid>>2, bsoff = (tid&3)*8;
  f32x4 acc[RT];
  #pragma unroll
  for (int r=0;r<RT;r++) acc[r] = (f32x4){0.f,0.f,0.f,0.f};
  int arow = -1;
  {
    int gr = bm + arow_s;
    if (gr < M) arow = GATHER ? idx[gr] : gr;
  }
  int bcol = bn + bsrow;
  for (int k0=0;k0<K;k0+=32){
    #pragma unroll
    for (int i=0;i<EPT;i++){
      float v = 0.0f;
      if (arow>=0){
        if (ARBF){
          float r = A[arow];
          int kk = k0 + aoff + i;
          float t = (r - cen[kk]) / wid[kk];
          v = expf(-0.5f*t*t);
        } else {
          v = A[(size_t)arow*K + k0 + aoff + i];
        }
      }
      unsigned short h = f2b(v);
      Asb[arow_s*40 + aoff + i] = h;
      if (SPLIT) Asb[MT*40 + arow_s*40 + aoff + i] = f2b(v - b2f(h));
    }
    #pragma unroll
    for (int i=0;i<8;i++){
      float v = 0.0f;
      if (bcol < Nd) v = TB ? B[(size_t)bcol*K + k0 + bsoff + i] : B[(size_t)(k0+bsoff+i)*Nd + bcol];
      unsigned short h = f2b(v);
      Btb[bsrow*40 + bsoff + i] = h;
      if (SPLIT) Btb[2560 + bsrow*40 + bsoff + i] = f2b(v - b2f(h));
    }
    __syncthreads();
    int boff = (wave*16 + (lane&15))*40 + (lane>>4)*8;
    bf16x8 bh = *(const bf16x8*)&Btb[boff];
    #pragma unroll
    for (int r=0;r<RT;r++){
      int aoff2 = (r*16 + (lane&15))*40 + (lane>>4)*8;
      bf16x8 ah = *(const bf16x8*)&Asb[aoff2];
      acc[r] = __builtin_amdgcn_mfma_f32_16x16x32_bf16(ah, bh, acc[r], 0,0,0);
      if (SPLIT){
        bf16x8 bl = *(const bf16x8*)&Btb[2560 + boff];
        bf16x8 al = *(const bf16x8*)&Asb[MT*40 + aoff2];
        acc[r] = __builtin_amdgcn_mfma_f32_16x16x32_bf16(ah, bl, acc[r], 0,0,0);
        acc[r] = __builtin_amdgcn_mfma_f32_16x16x32_bf16(al, bh, acc[r], 0,0,0);
      }
    }
    __syncthreads();
  }
  int col = bn + wave*16 + (lane&15);
  if (col < Nd){
    #pragma unroll
    for (int r=0;r<RT;r++){
      #pragma unroll
      for (int v=0;v<4;v++){
        int row = bm + r*16 + (lane>>4)*4 + v;
        if (row >= M) continue;
        size_t o = (size_t)row*Nd + col;
        float x = acc[r][v];
        if (ACC) x += (Dacc ? Dacc[o] : C[o]);
        if (DMUL) x *= dsiluf(dm[o]);
        if (PREOUT) pre[o] = x;
        if (ACT == 1) x = siluf(x);
        else if (ACT == 2) x = tanhf(x);
        else if (ACT == 3) x = sigf(x);
        C[o] = x;
      }
    }
  }
}

// --- fused radial MLP: H2 = silu( silu(RBF@W1) @ W2 ); PRE: also write pre-activations.
//     Bit-identical to the unfused pair: H1 is silu'ed, f2b-quantized (hi/lo for SPLIT) exactly
//     as the second GEMM's A-staging would do. M-tile 64, K1=128, N1=K2=N2=64. ---
template<bool SPLIT, bool PRE>
__global__ __launch_bounds__(256) void k_mlp2(
    const float* __restrict__ Rr, const float* __restrict__ cen, const float* __restrict__ wid,
    const float* __restrict__ W1, const float* __restrict__ W2,
    float* __restrict__ H2o, float* __restrict__ PRE1, float* __restrict__ PRE2, int M)
{
  __shared__ unsigned short Asb[(SPLIT?2:1)*2560];
  __shared__ unsigned short Btb[(SPLIT?2:1)*2560];
  __shared__ unsigned short As2[(SPLIT?2:1)*5120];   // H1 bf16: [kstep][row*40 + k%32]
  const int bm = blockIdx.x*64;
  const int tid = threadIdx.x, wave = tid>>6, lane = tid&63;
  const int arow_s = tid>>2, aoff = (tid&3)*8;
  const int bsrow = tid>>2, bsoff = (tid&3)*8;
  f32x4 acc[4];
  #pragma unroll
  for (int r=0;r<4;r++) acc[r] = (f32x4){0.f,0.f,0.f,0.f};
  int arow = -1;
  { int gr = bm + arow_s; if (gr < M) arow = gr; }
  float rv = (arow>=0) ? Rr[arow] : 0.0f;
  // ---- phase 1: H1 = RBF @ W1 ----
  for (int k0=0;k0<128;k0+=32){
    #pragma unroll
    for (int i=0;i<8;i++){
      float v = 0.0f;
      if (arow>=0){
        int kk = k0 + aoff + i;
        float t = (rv - cen[kk]) / wid[kk];
        v = expf(-0.5f*t*t);
      }
      unsigned short h = f2b(v);
      Asb[arow_s*40 + aoff + i] = h;
      if (SPLIT) Asb[2560 + arow_s*40 + aoff + i] = f2b(v - b2f(h));
    }
    #pragma unroll
    for (int i=0;i<8;i++){
      float v = W1[(size_t)(k0+bsoff+i)*64 + bsrow];
      unsigned short h = f2b(v);
      Btb[bsrow*40 + bsoff + i] = h;
      if (SPLIT) Btb[2560 + bsrow*40 + bsoff + i] = f2b(v - b2f(h));
    }
    __syncthreads();
    int boff = (wave*16 + (lane&15))*40 + (lane>>4)*8;
    bf16x8 bh = *(const bf16x8*)&Btb[boff];
    #pragma unroll
    for (int r=0;r<4;r++){
      int aoff2 = (r*16 + (lane&15))*40 + (lane>>4)*8;
      bf16x8 ah = *(const bf16x8*)&Asb[aoff2];
      acc[r] = __builtin_amdgcn_mfma_f32_16x16x32_bf16(ah, bh, acc[r], 0,0,0);
      if (SPLIT){
        bf16x8 bl = *(const bf16x8*)&Btb[2560 + boff];
        bf16x8 al = *(const bf16x8*)&Asb[2560 + aoff2];
        acc[r] = __builtin_amdgcn_mfma_f32_16x16x32_bf16(ah, bl, acc[r], 0,0,0);
        acc[r] = __builtin_amdgcn_mfma_f32_16x16x32_bf16(al, bh, acc[r], 0,0,0);
      }
    }
    __syncthreads();
  }
  // ---- epilogue 1: silu (+PRE1) -> pack H1 into As2 (exactly the old restaging quantization) ----
  {
    int col = wave*16 + (lane&15);
    #pragma unroll
    for (int r=0;r<4;r++){
      #pragma unroll
      for (int v=0;v<4;v++){
        int lrow = r*16 + (lane>>4)*4 + v;
        int row = bm + lrow;
        float x = acc[r][v];
        if (PRE && row < M) PRE1[(size_t)row*64 + col] = x;
        x = siluf(x);
        unsigned short h = f2b(x);
        As2[(col>>5)*2560 + lrow*40 + (col&31)] = h;
        if (SPLIT) As2[5120 + (col>>5)*2560 + lrow*40 + (col&31)] = f2b(x - b2f(h));
        acc[r][v] = 0.0f;
      }
    }
  }
  __syncthreads();
  // ---- phase 2: H2 = H1 @ W2 ----
  for (int k0=0;k0<64;k0+=32){
    #pragma unroll
    for (int i=0;i<8;i++){
      float v = W2[(size_t)(k0+bsoff+i)*64 + bsrow];
      unsigned short h = f2b(v);
      Btb[bsrow*40 + bsoff + i] = h;
      if (SPLIT) Btb[2560 + bsrow*40 + bsoff + i] = f2b(v - b2f(h));
    }
    __syncthreads();
    int boff = (wave*16 + (lane&15))*40 + (lane>>4)*8;
    bf16x8 bh = *(const bf16x8*)&Btb[boff];
    int ksel = (k0>>5)*2560;
    #pragma unroll
    for (int r=0;r<4;r++){
      int aoff2 = ksel + (r*16 + (lane&15))*40 + (lane>>4)*8;
      bf16x8 ah = *(const bf16x8*)&As2[aoff2];
      acc[r] = __builtin_amdgcn_mfma_f32_16x16x32_bf16(ah, bh, acc[r], 0,0,0);
      if (SPLIT){
        bf16x8 bl = *(const bf16x8*)&Btb[2560 + boff];
        bf16x8 al = *(const bf16x8*)&As2[5120 + aoff2];
        acc[r] = __builtin_amdgcn_mfma_f32_16x16x32_bf16(ah, bl, acc[r], 0,0,0);
        acc[r] = __builtin_amdgcn_mfma_f32_16x16x32_bf16(al, bh, acc[r], 0,0,0);
      }
    }
    __syncthreads();
  }
  // ---- epilogue 2 ----
  {
    int col = wave*16 + (lane&15);
    #pragma unroll
    for (int r=0;r<4;r++){
      #pragma unroll
      for (int v=0;v<4;v++){
        int row = bm + r*16 + (lane>>4)*4 + v;
        if (row >= M) continue;
        float x = acc[r][v];
        if (PRE) PRE2[(size_t)row*64 + col] = x;
        H2o[(size_t)row*64 + col] = siluf(x);
      }
    }
  }
}

// --- fused attention-logit GEMM: Zc = tanh([f0[src]|f0[dst]|H2] @ WZ) (K=320, Nd=32)
//     LAMB: also LAM[row] = exp( sum_c Zc[row][c]*wa[c] ) ---
template<bool SPLIT, bool LAMB>
__global__ __launch_bounds__(256) void k_zgemm(
    const float* __restrict__ F0, const int* __restrict__ sidx, const int* __restrict__ didx,
    const float* __restrict__ H2v, const float* __restrict__ WZ, const float* __restrict__ wa,
    float* __restrict__ Zc, float* __restrict__ LAM, int M)
{
  __shared__ unsigned short Asb[(SPLIT?2:1)*64*40];
  __shared__ unsigned short Btb[(SPLIT?2:1)*2560];
  __shared__ float lacc[128];
  const int bm = blockIdx.x*64;
  const int tid = threadIdx.x, wave = tid>>6, lane = tid&63;
  const int arow_s = tid>>2, aoff = (tid&3)*8;
  const int bsrow = tid>>2, bsoff = (tid&3)*8;
  f32x4 acc[4];
  #pragma unroll
  for (int r=0;r<4;r++) acc[r] = (f32x4){0.f,0.f,0.f,0.f};
  long sb=-1, db=-1, hb=-1;
  {
    int gr = bm + arow_s;
    if (gr < M){ sb=(long)sidx[gr]*128; db=(long)didx[gr]*128; hb=(long)gr*64; }
  }
  for (int k0=0;k0<320;k0+=32){
    long ab; int rk; const float* sp;
    if (k0 < 128){ ab=sb; rk=k0; sp=F0; }
    else if (k0 < 256){ ab=db; rk=k0-128; sp=F0; }
    else { ab=hb; rk=k0-256; sp=H2v; }
    #pragma unroll
    for (int i=0;i<8;i++){
      float v = (ab>=0) ? sp[ab + rk + aoff + i] : 0.0f;
      unsigned short h = f2b(v);
      Asb[arow_s*40 + aoff + i] = h;
      if (SPLIT) Asb[64*40 + arow_s*40 + aoff + i] = f2b(v - b2f(h));
    }
    #pragma unroll
    for (int i=0;i<8;i++){
      int kk = k0 + bsoff + i;
      float v = (bsrow < 32) ? WZ[kk*32 + bsrow] : 0.0f;
      unsigned short h = f2b(v);
      Btb[bsrow*40 + bsoff + i] = h;
      if (SPLIT) Btb[2560 + bsrow*40 + bsoff + i] = f2b(v - b2f(h));
    }
    __syncthreads();
    int boff = (wave*16 + (lane&15))*40 + (lane>>4)*8;
    bf16x8 bh = *(const bf16x8*)&Btb[boff];
    #pragma unroll
    for (int r=0;r<4;r++){
      int aoff2 = (r*16 + (lane&15))*40 + (lane>>4)*8;
      bf16x8 ah = *(const bf16x8*)&Asb[aoff2];
      acc[r] = __builtin_amdgcn_mfma_f32_16x16x32_bf16(ah, bh, acc[r], 0,0,0);
      if (SPLIT){
        bf16x8 bl = *(const bf16x8*)&Btb[2560 + boff];
        bf16x8 al = *(const bf16x8*)&Asb[64*40 + aoff2];
        acc[r] = __builtin_amdgcn_mfma_f32_16x16x32_bf16(ah, bl, acc[r], 0,0,0);
        acc[r] = __builtin_amdgcn_mfma_f32_16x16x32_bf16(al, bh, acc[r], 0,0,0);
      }
    }
    __syncthreads();
  }
  int col = wave*16 + (lane&15);
  if (wave < 2){   // cols 0..31
    #pragma unroll
    for (int r=0;r<4;r++){
      #pragma unroll
      for (int v=0;v<4;v++){
        int row = bm + r*16 + (lane>>4)*4 + v;
        float z = tanhf(acc[r][v]);
        if (row < M) Zc[(size_t)row*32 + col] = z;
        if (LAMB){
          float p = (row < M) ? z*wa[col] : 0.0f;
          #pragma unroll
          for (int o=8;o>0;o>>=1) p += __shfl_xor(p, o, 64);
          if ((lane&15)==0) lacc[wave*64 + r*16 + (lane>>4)*4 + v] = p;
        }
      }
    }
  }
  if (LAMB){
    __syncthreads();
    if (tid < 64){
      int row = bm + tid;
      if (row < M) LAM[row] = expf(lacc[tid] + lacc[64+tid]);
    }
  }
}

// ---------- bf16 MFMA einsum (X-strided rows); SPLIT => split-bf16; GATE: C[o]=A[o]+x*P; Dacc acc source ----------
template<int CI, int CO, int X, bool TB, bool ACC, bool GATHER, bool SPLIT, bool GATE>
__global__ __launch_bounds__(256) void k_meinsum(
    const float* __restrict__ A, const int* __restrict__ idx,
    const float* __restrict__ W, float* __restrict__ C, int M,
    const float* __restrict__ P, int PS, int POFF, const float* __restrict__ Dacc)
{
  __shared__ unsigned short Asb[(SPLIT?2:1)*2560];
  __shared__ unsigned short Btb[(SPLIT?2:1)*2560];
  const int bm = blockIdx.x*64;
  const int tid = threadIdx.x, wave = tid>>6, lane = tid&63;
  const int srow = tid>>2, soff = (tid&3)*8;
  f32x4 acc[4];
  #pragma unroll
  for (int r=0;r<4;r++) acc[r] = (f32x4){0.f,0.f,0.f,0.f};
  long abase = -1;
  {
    int grow = bm + srow;
    if (grow < M*X){
      int ge = grow / X, gx = grow - ge*X;
      int ar = GATHER ? idx[ge] : ge;
      abase = (long)ar*CI*X + gx;
    }
  }
  for (int k0=0;k0<CI;k0+=32){
    #pragma unroll
    for (int i=0;i<8;i++){
      float v = (abase>=0) ? A[abase + (size_t)(k0+soff+i)*X] : 0.0f;
      unsigned short h = f2b(v);
      Asb[srow*40 + soff + i] = h;
      if (SPLIT) Asb[2560 + srow*40 + soff + i] = f2b(v - b2f(h));
    }
    #pragma unroll
    for (int i=0;i<8;i++){
      int kk = k0 + soff + i;
      float v = 0.0f;
      if (srow < CO) v = TB ? W[srow*CI + kk] : W[kk*CO + srow];
      unsigned short h = f2b(v);
      Btb[srow*40 + soff + i] = h;
      if (SPLIT) Btb[2560 + srow*40 + soff + i] = f2b(v - b2f(h));
    }
    __syncthreads();
    int boff = (wave*16 + (lane&15))*40 + (lane>>4)*8;
    bf16x8 bh = *(const bf16x8*)&Btb[boff];
    #pragma unroll
    for (int r=0;r<4;r++){
      int aoff = (r*16 + (lane&15))*40 + (lane>>4)*8;
      bf16x8 ah = *(const bf16x8*)&Asb[aoff];
      acc[r] = __builtin_amdgcn_mfma_f32_16x16x32_bf16(ah, bh, acc[r], 0,0,0);
      if (SPLIT){
        bf16x8 bl = *(const bf16x8*)&Btb[2560 + boff];
        bf16x8 al = *(const bf16x8*)&Asb[2560 + aoff];
        acc[r] = __builtin_amdgcn_mfma_f32_16x16x32_bf16(ah, bl, acc[r], 0,0,0);
        acc[r] = __builtin_amdgcn_mfma_f32_16x16x32_bf16(al, bh, acc[r], 0,0,0);
      }
    }
    __syncthreads();
  }
  int col = wave*16 + (lane&15);
  if (col < CO){
    #pragma unroll
    for (int r=0;r<4;r++){
      #pragma unroll
      for (int v=0;v<4;v++){
        int row = bm + r*16 + (lane>>4)*4 + v;
        if (row >= M*X) continue;
        int ge = row / X, gx = row - ge*X;
        size_t o = (size_t)ge*CO*X + (size_t)col*X + gx;
        float xx = acc[r][v];
        if (GATE){
          float p = P[(size_t)ge*PS + POFF + col];
          C[o] = A[o] + xx*p;   // CI==CO => A layout == C layout
        } else {
          if (ACC) xx += (Dacc ? Dacc[o] : C[o]);
          C[o] = xx;
        }
      }
    }
  }
}

// ------------------------- small kernels -------------------------
__global__ void k_sentinel(float* o, int n, float v){
  int i = blockIdx.x*256 + threadIdx.x;
  if (i < n) o[i] = v;
}

__global__ void k_geom(const float* __restrict__ pos, const int* __restrict__ src, const int* __restrict__ dst,
                       float* __restrict__ U, float* __restrict__ Rr, float* __restrict__ SH2b){
  int e = blockIdx.x*256 + threadIdx.x;
  if (e >= NE) return;
  int s = src[e], d = dst[e];
  float vx = pos[s*3+0]-pos[d*3+0];
  float vy = pos[s*3+1]-pos[d*3+1];
  float vz = pos[s*3+2]-pos[d*3+2];
  float r = sqrtf(vx*vx+vy*vy+vz*vz + 1e-12f);
  float ux=vx/r, uy=vy/r, uz=vz/r;
  U[e*3+0]=ux; U[e*3+1]=uy; U[e*3+2]=uz;
  Rr[e]=r;
  SH2b[e*5+0]=SQ15F*ux*uy;
  SH2b[e*5+1]=SQ15F*uy*uz;
  SH2b[e*5+2]=0.5f*SQ5F*(3.0f*uz*uz-1.0f);
  SH2b[e*5+3]=SQ15F*ux*uz;
  SH2b[e*5+4]=0.5f*SQ15F*(ux*ux-uy*uy);
}

__global__ void k_f0init(const int* __restrict__ na, const float* __restrict__ at, float* __restrict__ f0){
  int t = blockIdx.x*256 + threadIdx.x;
  if (t >= NN*128) return;
  int n = t>>7, j = t&127;
  int m = c_amap[na[n]];
  f0[t] = at[m*128+j];
}

// fused post-block: AB normalize + finy residual + bf16 checkpoint
__global__ void k_postblk(const float* __restrict__ x0,const float* __restrict__ x1,const float* __restrict__ x2,
                          float* __restrict__ y0,float* __restrict__ y1,float* __restrict__ y2,
                          const float* __restrict__ S, unsigned short* __restrict__ ck,
                          const float* __restrict__ Pl, const int* __restrict__ dst, float* __restrict__ AB){
  int t = blockIdx.x*256 + threadIdx.x;
  if (t < NE) AB[t] = Pl[t]/(S[dst[t]]+1e-9f);
  if (t >= NN*480) return;
  float v;
  if (t < NN*128){ int n=t>>7; v = x0[t] + y0[t]/(S[n]+1e-9f); y0[t]=v; }
  else if (t < NN*320){ int q=t-NN*128; int n=q/192; v = x1[q] + y1[q]/(S[n]+1e-9f); y1[q]=v; }
  else { int q=t-NN*320; int n=q/160; v = x2[q] + y2[q]/(S[n]+1e-9f); y2[q]=v; }
  ck[t] = f2b(v);
}

// bf16 checkpoint quant
__global__ void k_q3(const float* __restrict__ f0,const float* __restrict__ f1,const float* __restrict__ f2,
                     unsigned short* __restrict__ ck){
  int t = blockIdx.x*256 + threadIdx.x;
  if (t >= NN*480) return;
  float v;
  if (t < NN*128) v = f0[t];
  else if (t < NN*320) v = f1[t-NN*128];
  else v = f2[t-NN*320];
  ck[t] = f2b(v);
}
// dual dequant
__global__ void k_dq3x2(const unsigned short* __restrict__ cka, const unsigned short* __restrict__ ckb,
                        float* __restrict__ a0,float* __restrict__ a1,float* __restrict__ a2,
                        float* __restrict__ b0,float* __restrict__ b1,float* __restrict__ b2){
  int t = blockIdx.x*256 + threadIdx.x;
  if (t >= NN*480) return;
  float va = b2f(cka[t]), vb = b2f(ckb[t]);
  if (t < NN*128){ a0[t]=va; b0[t]=vb; }
  else if (t < NN*320){ int q=t-NN*128; a1[q]=va; b1[q]=vb; }
  else { int q=t-NN*320; a2[q]=va; b2[q]=vb; }
}

// per-graph aggregation; SC strided 352 [sv0|sw0|sw1|sw2]; accumulates S in lanes 480..495
template<bool INIT>
__global__ __launch_bounds__(512) void k_agg(
  float* __restrict__ f0o,float* __restrict__ f1o,float* __restrict__ f2o,
  const float* __restrict__ SC,const float* __restrict__ sv1,const float* __restrict__ sv2,
  const float* __restrict__ g,const float* __restrict__ U,const float* __restrict__ SH2b,
  const float* __restrict__ aArr,const int* __restrict__ keys,const int* __restrict__ dst,
  float* __restrict__ SACC, int c0, int c1)
{
  __shared__ float acc[7680];
  int b = blockIdx.x, lo = b<<4;
  int e0 = lbound(keys, NE, lo), e1 = lbound(keys, NE, lo+16);
  if (e0 < c0) e0 = c0;
  if (e1 > c1) e1 = c1;
  if (e0 >= e1) return;
  for (int i=threadIdx.x;i<7680;i+=512) acc[i]=0.0f;
  __syncthreads();
  const int j = threadIdx.x;
  const float inv = 1.0f/sqrtf(15.57f);
  int cat=3, cc_=0, xx_=0;
  if (j<128){ cat=0; }
  else if (j<320){ cat=1; int t=j-128; cc_=t/3; xx_=t-3*cc_; }
  else if (j<480){ cat=2; int t=j-320; cc_=t/5; xx_=t-5*cc_; }
  float sacc=0.0f;
  for (int e=e0; e<e1; ++e){
    int el = e - c0;
    float a = INIT ? inv : aArr[e];
    int nl = dst[e]&15;
    if (cat==0){
      float m = INIT ? g[el*224+j] : (SC[(size_t)el*352+j]*g[el*224+j] + SC[(size_t)el*352+128+j]);
      acc[nl*480+j] += a*m;
    } else if (cat==1){
      int t=j-128;
      float sh = SQ3F*U[e*3+xx_];
      float m = INIT ? g[el*224+128+cc_]*sh : (sv1[el*192+t]*g[el*224+128+cc_] + SC[(size_t)el*352+256+cc_]*sh);
      acc[nl*480+j] += a*m;
    } else if (cat==2){
      int t=j-320;
      float sh = SH2b[e*5+xx_];
      float m = INIT ? g[el*224+192+cc_]*sh : (sv2[el*160+t]*g[el*224+192+cc_] + SC[(size_t)el*352+320+cc_]*sh);
      acc[nl*480+j] += a*m;
    } else if (!INIT && j<496){
      if (nl==(j-480)) sacc += a;
    }
  }
  __syncthreads();
  for (int i=threadIdx.x;i<7680;i+=512){
    int nl=i/480, jj=i-480*nl, n=lo+nl;
    float v=acc[i];
    if (jj<128) f0o[n*128+jj]+=v;
    else if (jj<320) f1o[n*192+jj-128]+=v;
    else f2o[n*160+jj-320]+=v;
  }
  if (!INIT && j>=480 && j<496) SACC[lo+(j-480)] += sacc;
}

// per-graph scatter of edge grads
__global__ __launch_bounds__(640) void k_scat(
  float* __restrict__ df0, float* __restrict__ df1, float* __restrict__ df2,
  const float* __restrict__ DE0, const float* __restrict__ DZD,
  const float* __restrict__ DE1, const float* __restrict__ DE2,
  const int* __restrict__ src, const int* __restrict__ dst, int c0, int c1)
{
  __shared__ float acc[7680];
  int b=blockIdx.x, lo=b<<4;
  int e0=lbound(dst,NE,lo), e1=lbound(dst,NE,lo+16);
  if (e0 < c0) e0 = c0;
  if (e1 > c1) e1 = c1;
  for (int i=threadIdx.x;i<7680;i+=640) acc[i]=0.0f;
  __syncthreads();
  const int j=threadIdx.x;
  for (int e=e0;e<e1;++e){
    int el=e-c0;
    int sl=(src[e]&15)*480, dl=(dst[e]&15)*480;
    if (j<128) acc[sl+j] += DE0[el*128+j];
    else if (j<256){ int q=j-128; acc[dl+q] += DZD[el*128+q]; }
    else if (j<448){ int q=j-256; acc[sl+128+q] += DE1[el*192+q]; }
    else if (j<608){ int q=j-448; acc[sl+320+q] += DE2[el*160+q]; }
    __syncthreads();
  }
  for (int i=threadIdx.x;i<7680;i+=640){
    int nl=i/480, jj=i-480*nl, n=lo+nl;
    float v=acc[i];
    if (jj<128) df0[n*128+jj]+=v;
    else if (jj<320) df1[n*192+jj-128]+=v;
    else f2o_dummy: df2[n*160+jj-320]+=v;
  }
}

// SSUM[n] = (FB[n]-FA[n]) . DY[n]; also DI* = DY* (fold the 3 memcpys)
__global__ __launch_bounds__(256) void k_ssum(
  const float* __restrict__ FA0,const float* __restrict__ FA1,const float* __restrict__ FA2,
  const float* __restrict__ FB0,const float* __restrict__ FB1,const float* __restrict__ FB2,
  const float* __restrict__ DY0,const float* __restrict__ DY1,const float* __restrict__ DY2,
  float* __restrict__ SSUM,
  float* __restrict__ DI0o, float* __restrict__ DI1o, float* __restrict__ DI2o)
{
  int n=blockIdx.x*4+(threadIdx.x>>6), lane=threadIdx.x&63;
  if (n>=NN) return;
  float s=0.0f;
  for (int j=lane;j<480;j+=64){
    float d,g;
    if (j<128){ d=FB0[n*128+j]-FA0[n*128+j]; g=DY0[n*128+j]; DI0o[n*128+j]=g; }
    else if (j<320){ int q=j-128; d=FB1[n*192+q]-FA1[n*192+q]; g=DY1[n*192+q]; DI1o[n*192+q]=g; }
    else { int q=j-320; d=FB2[n*160+q]-FA2[n*160+q]; g=DY2[n*160+q]; DI2o[n*160+q]=g; }
    s += d*g;
  }
  s = wred64(s);
  if (lane==0) SSUM[n]=s;
}

// fused backward edge chain: da -> dlam -> dz -> split0/1/2 ; one wave per edge
__global__ __launch_bounds__(256) void k_bedge(
  float* __restrict__ SC, float* __restrict__ SV1, float* __restrict__ SV2,
  const float* __restrict__ g, const float* __restrict__ U, const float* __restrict__ SH2b,
  const float* __restrict__ df0,const float* __restrict__ df1,const float* __restrict__ df2,
  const int* __restrict__ dst, const float* __restrict__ SSUM, const float* __restrict__ wa,
  float* __restrict__ Z, const float* __restrict__ aArr,
  float* __restrict__ DG, float* __restrict__ DSH1, float* __restrict__ DSH2,
  int c0, int cnt)
{
  int w=threadIdx.x>>6, lane=threadIdx.x&63;
  int el=blockIdx.x*4+w;
  if (el>=cnt) return;
  int e=c0+el;
  int d=dst[e];
  float s=0.0f;
  for (int j=lane;j<480;j+=64){
    float m, dfv;
    if (j<128){
      m = SC[(size_t)el*352+j]*g[el*224+j] + SC[(size_t)el*352+128+j];
      dfv = df0[(size_t)d*128+j];
    } else if (j<320){
      int t=j-128, c=t/3, x=t-3*c;
      m = SV1[el*192+t]*g[el*224+128+c] + SC[(size_t)el*352+256+c]*(SQ3F*U[e*3+x]);
      dfv = df1[(size_t)d*192+t];
    } else {
      int t=j-320, c=t/5, x=t-5*c;
      m = SV2[el*160+t]*g[el*224+192+c] + SC[(size_t)el*352+320+c]*SH2b[e*5+x];
      dfv = df2[(size_t)d*160+t];
    }
    s += m*dfv;
  }
  s = wred64(s);
  s = __shfl(s,0,64);
  float a = aArr[e];
  float dlam = a*(s - SSUM[d]);
  if (lane<32){
    float z = Z[(size_t)el*32+lane];
    Z[(size_t)el*32+lane] = dlam*wa[lane]*(1.0f-z*z);
  }
  {
    float* row = SC + (size_t)el*352;
    for (int j=lane;j<128;j+=64){
      float dm = a*df0[(size_t)d*128+j];
      float sv = row[j];
      row[128+j] = dm;
      row[j] = dm*g[el*224+j];
      DG[el*224+j] = dm*sv;
    }
  }
  {
    float dm0=a*df1[(size_t)d*192+lane*3+0];
    float dm1=a*df1[(size_t)d*192+lane*3+1];
    float dm2=a*df1[(size_t)d*192+lane*3+2];
    float sw1o=SC[(size_t)el*352+256+lane];
    float g1=g[el*224+128+lane];
    float c0v=dm0*sw1o, c1v=dm1*sw1o, c2v=dm2*sw1o;
    c0v=wred64(c0v); c1v=wred64(c1v); c2v=wred64(c2v);
    if (lane==0){ DSH1[e*3+0]+=c0v; DSH1[e*3+1]+=c1v; DSH1[e*3+2]+=c2v; }
    float sh0=SQ3F*U[e*3+0], sh1=SQ3F*U[e*3+1], sh2=SQ3F*U[e*3+2];
    SC[(size_t)el*352+256+lane]=dm0*sh0+dm1*sh1+dm2*sh2;
    float sv0o=SV1[el*192+lane*3+0], sv1o=SV1[el*192+lane*3+1], sv2o=SV1[el*192+lane*3+2];
    DG[el*224+128+lane]=dm0*sv0o+dm1*sv1o+dm2*sv2o;
    SV1[el*192+lane*3+0]=dm0*g1; SV1[el*192+lane*3+1]=dm1*g1; SV1[el*192+lane*3+2]=dm2*g1;
  }
  {
    float dm[5]={0,0,0,0,0}, svo[5]={0,0,0,0,0};
    float sw2o=0.0f, g2=0.0f;
    if (lane<32){
      #pragma unroll
      for (int x=0;x<5;x++){ dm[x]=a*df2[(size_t)d*160+lane*5+x]; svo[x]=SV2[el*160+lane*5+x]; }
      sw2o=SC[(size_t)el*352+320+lane]; g2=g[el*224+192+lane];
    }
    float c[5];
    #pragma unroll
    for (int x=0;x<5;x++){ c[x]=dm[x]*sw2o; c[x]=wred64(c[x]); }
    if (lane==0){
      #pragma unroll
      for (int x=0;x<5;x++) DSH2[e*5+x]+=c[x];
    }
    if (lane<32){
      float dsw=0.0f, dg2=0.0f;
      #pragma unroll
      for (int x=0;x<5;x++){ dsw+=dm[x]*SH2b[e*5+x]; dg2+=dm[x]*svo[x]; }
      SC[(size_t)el*352+320+lane]=dsw;
      DG[el*224+192+lane]=dg2;
      #pragma unroll
      for (int x=0;x<5;x++) SV2[el*160+lane*5+x]=dm[x]*g2;
    }
  }
}

// fused gate backward (both gate blocks in one launch)
__global__ void k_gateback2(const float* __restrict__ dfB1, float* __restrict__ V1,
                            const float* __restrict__ dfB2, float* __restrict__ V2,
                            const float* __restrict__ P12, float* __restrict__ DPa){
  int t=blockIdx.x*256+threadIdx.x;
  if (t < NN*64){
    int n=t>>6, d=t&63;
    float p=P12[(size_t)n*96+d];
    float dp=0.0f;
    #pragma unroll
    for (int x=0;x<3;x++){ dp += dfB1[(size_t)t*3+x]*V1[(size_t)t*3+x]; }
    #pragma unroll
    for (int x=0;x<3;x++){ V1[(size_t)t*3+x] = dfB1[(size_t)t*3+x]*p; }
    DPa[(size_t)n*96+d] = dp*p*(1.0f-p);
  } else if (t < NN*96){
    int t2=t-NN*64;
    int n=t2>>5, d=t2&31;
    float p=P12[(size_t)n*96+64+d];
    float dp=0.0f;
    #pragma unroll
    for (int x=0;x<5;x++){ dp += dfB2[(size_t)t2*5+x]*V2[(size_t)t2*5+x]; }
    #pragma unroll
    for (int x=0;x<5;x++){ V2[(size_t)t2*5+x] = dfB2[(size_t)t2*5+x]*p; }
    DPa[(size_t)n*96+64+d] = dp*p*(1.0f-p);
  }
}

__global__ __launch_bounds__(256) void k_dr(const float* __restrict__ DRBF, const float* __restrict__ Rr,
    const float* __restrict__ cen, const float* __restrict__ wid, float* __restrict__ DRa, int c0, int cnt){
  int w=threadIdx.x>>6, lane=threadIdx.x&63;
  int el=blockIdx.x*4+w;
  if (el>=cnt) return;
  int e=c0+el;
  float r=Rr[e], s=0.0f;
  for (int k=lane;k<128;k+=64){
    float c=cen[k], wd=wid[k];
    float t=(r-c)/wd;
    float rb=expf(-0.5f*t*t);
    s += DRBF[el*128+k]*rb*((c-r)/(wd*wd));
  }
  s=wred64(s);
  if (lane==0) DRa[e]+=s;
}

__global__ __launch_bounds__(256) void k_initback(
  const float* __restrict__ df0,const float* __restrict__ df1,const float* __restrict__ df2,
  const int* __restrict__ dst,
  const float* __restrict__ g,const float* __restrict__ U,const float* __restrict__ SH2b,
  float* __restrict__ DG,float* __restrict__ DSH1,float* __restrict__ DSH2, int c0, int cnt)
{
  int w=threadIdx.x>>6, lane=threadIdx.x&63;
  int el=blockIdx.x*4+w;
  if (el>=cnt) return;
  int e=c0+el;
  int d=dst[e];
  const float inv=1.0f/sqrtf(15.57f);
  for (int j=lane;j<128;j+=64) DG[el*224+j]=inv*df0[d*128+j];
  float sh0=SQ3F*U[e*3+0], sh1=SQ3F*U[e*3+1], sh2=SQ3F*U[e*3+2];
  float df10=df1[d*192+lane*3+0], df11=df1[d*192+lane*3+1], df12=df1[d*192+lane*3+2];
  float g1=g[el*224+128+lane];
  DG[el*224+128+lane]=inv*(df10*sh0+df11*sh1+df12*sh2);
  float c0v=g1*df10, c1v=g1*df11, c2v=g1*df12;
  c0v=wred64(c0v); c1v=wred64(c1v); c2v=wred64(c2v);
  if (lane==0){ DSH1[e*3+0]+=inv*c0v; DSH1[e*3+1]+=inv*c1v; DSH1[e*3+2]+=inv*c2v; }
  float cc[5]={0,0,0,0,0};
  if (lane<32){
    float g2=g[el*224+192+lane];
    float dgv=0.0f;
    #pragma unroll
    for (int x=0;x<5;x++){ float dfv=df2[d*160+lane*5+x]; dgv+=dfv*SH2b[e*5+x]; cc[x]=g2*dfv; }
    DG[el*224+192+lane]=inv*dgv;
  }
  #pragma unroll
  for (int x=0;x<5;x++) cc[x]=wred64(cc[x]);
  if (lane==0){
    #pragma unroll
    for (int x=0;x<5;x++) DSH2[e*5+x]+=inv*cc[x];
  }
}

__global__ void k_geoback(const float* __restrict__ DRa, const float* __restrict__ DSH1, const float* __restrict__ DSH2,
                          const float* __restrict__ U, const float* __restrict__ Rr,
                          const int* __restrict__ src, const int* __restrict__ dst,
                          float* __restrict__ DPOS){
  int e=blockIdx.x*256+threadIdx.x;
  if (e>=NE) return;
  float ux=U[e*3+0], uy=U[e*3+1], uz=U[e*3+2];
  float r=Rr[e];
  float dux=SQ3F*DSH1[e*3+0], duy=SQ3F*DSH1[e*3+1], duz=SQ3F*DSH1[e*3+2];
  float d0=DSH2[e*5+0],d1=DSH2[e*5+1],d2=DSH2[e*5+2],d3=DSH2[e*5+3],d4=DSH2[e*5+4];
  dux += SQ15F*(uy*d0+uz*d3+ux*d4);
  duy += SQ15F*(ux*d0+uz*d1-uy*d4);
  duz += SQ15F*(uy*d1+ux*d3)+3.0f*SQ5F*uz*d2;
  float dr=DRa[e];
  float dot=dux*ux+duy*uy+duz*uz;
  float dvx=(dux-dot*ux)/r+dr*ux;
  float dvy=(duy-dot*uy)/r+dr*uy;
  float dvz=(duz-dot*uz)/r+dr*uz;
  int s=src[e], d=dst[e];
  atomicAdd(&DPOS[s*3+0],dvx); atomicAdd(&DPOS[s*3+1],dvy); atomicAdd(&DPOS[s*3+2],dvz);
  atomicAdd(&DPOS[d*3+0],-dvx); atomicAdd(&DPOS[d*3+1],-dvy); atomicAdd(&DPOS[d*3+2],-dvz);
}

__global__ void k_forces(const float* __restrict__ DPOS, float* __restrict__ o){
  int i=blockIdx.x*256+threadIdx.x;
  if (i<NN*3) o[i]=-DPOS[i];
}

// per-node LN + head forward + backward seeds; single wave per node
__global__ __launch_bounds__(64) void k_lnhead(
  const float* __restrict__ f0,const float* __restrict__ f1,const float* __restrict__ f2,
  const float* __restrict__ lng,const float* __restrict__ lnb,
  const float* __restrict__ W0,const float* __restrict__ hout,
  float* __restrict__ EN, float* __restrict__ df0,float* __restrict__ df1,float* __restrict__ df2)
{
  __shared__ float xh[480];
  __shared__ float fl[128];
  __shared__ float dyv[128];
  __shared__ float dxh[128];
  int n=blockIdx.x, lane=threadIdx.x;
  const float c0=1.0f/sqrtf(18.03f);
  for (int i=lane;i<480;i+=64){
    float v=(i<128)? f0[n*128+i] : (i<320)? f1[n*192+(i-128)] : f2[n*160+(i-320)];
    xh[i]=v;
  }
  __syncthreads();
  float s1=0.0f,s2=0.0f;
  for (int i=lane;i<480;i+=64){ float v=xh[i]; s1+=v; s2+=v*v; }
  s1=wred64(s1); s2=wred64(s2);
  float mu=__shfl(s1,0,64)*(1.0f/480.0f);
  float var=__shfl(s2,0,64)*(1.0f/480.0f)-mu*mu;
  float rstd=rsqrtf(var+1e-5f);
  for (int i=lane;i<480;i+=64) xh[i]=(xh[i]-mu)*rstd;
  __syncthreads();
  for (int k=lane;k<128;k+=64) fl[k]=xh[k]*lng[k]+lnb[k];
  __syncthreads();
  float y0=0.0f,y1=0.0f;
  for (int k=0;k<128;k++){ float f=fl[k]; y0+=f*W0[k*128+lane]; y1+=f*W0[k*128+lane+64]; }
  float e = siluf(y0)*hout[lane] + siluf(y1)*hout[lane+64];
  e=wred64(e);
  if (lane==0) EN[n]=e*c0;
  dyv[lane]=c0*hout[lane]*dsiluf(y0);
  dyv[lane+64]=c0*hout[lane+64]*dsiluf(y1);
  __syncthreads();
  float d0=0.0f,d1=0.0f;
  for (int j=0;j<128;j++){ float dv=dyv[j]; d0+=dv*W0[lane*128+j]; d1+=dv*W0[(lane+64)*128+j]; }
  dxh[lane]=d0*lng[lane];
  dxh[lane+64]=d1*lng[lane+64];
  __syncthreads();
  float s3=dxh[lane]+dxh[lane+64];
  float s4=dxh[lane]*xh[lane]+dxh[lane+64]*xh[lane+64];
  s3=wred64(s3); s4=wred64(s4);
  float m1=__shfl(s3,0,64)*(1.0f/480.0f);
  float m2=__shfl(s4,0,64)*(1.0f/480.0f);
  for (int i=lane;i<480;i+=64){
    float dv=rstd*(((i<128)?dxh[i]:0.0f)-m1-xh[i]*m2);
    if (i<128) df0[n*128+i]=dv;
    else if (i<320) df1[n*192+(i-128)]=dv;
    else df2[n*160+(i-320)]=dv;
  }
}

__global__ void k_esum(const float* __restrict__ EN, float* __restrict__ out){
  int b=blockIdx.x*64+threadIdx.x;
  if (b<NG){
    float s=0.0f;
    for (int k=0;k<16;k++) s+=EN[b*16+k];
    out[b]=s;
  }
}

#define MG(MT,TB,ACC,ACT,GA,SP,AR,DM,PO, A,IDX,B,C,M,Nd,K, CEN,WID,DMp,POp,DAp) \
  k_mgemm<MT,TB,ACC,ACT,GA,SP,AR,DM,PO><<<dim3((unsigned)(((M)+(MT)-1)/(MT)),(unsigned)(((Nd)+63)/64)),dim3(256),0,stream>>>((A),(IDX),(B),(C),(M),(Nd),(K),(CEN),(WID),(DMp),(POp),(DAp))
#define MGEMM(MT,TB,ACC,ACT,GA, A,IDX,B,C,M,Nd,K) MG(MT,TB,ACC,ACT,GA,false,false,false,false, A,IDX,B,C,M,Nd,K, nullptr,nullptr,nullptr,nullptr,nullptr)
#define MGEMMD(MT,TB,ACC,ACT,GA, A,IDX,B,C,M,Nd,K,DA) MG(MT,TB,ACC,ACT,GA,false,false,false,false, A,IDX,B,C,M,Nd,K, nullptr,nullptr,nullptr,nullptr,DA)
#define MGEMM3(MT,TB,ACC,ACT,GA, A,IDX,B,C,M,Nd,K) MG(MT,TB,ACC,ACT,GA,true,false,false,false, A,IDX,B,C,M,Nd,K, nullptr,nullptr,nullptr,nullptr,nullptr)
#define MEINS(CI,CO,X,TB,ACC,GA, A,IDX,Wt,C,M) \
  k_meinsum<CI,CO,X,TB,ACC,GA,false,false><<<dim3((unsigned)(((M)*(X)+63)/64)),dim3(256),0,stream>>>((A),(IDX),(Wt),(C),(M),nullptr,0,0,nullptr)
#define MEINSD(CI,CO,X,TB,ACC,GA, A,IDX,Wt,C,M,DA) \
  k_meinsum<CI,CO,X,TB,ACC,GA,false,false><<<dim3((unsigned)(((M)*(X)+63)/64)),dim3(256),0,stream>>>((A),(IDX),(Wt),(C),(M),nullptr,0,0,(DA))
#define MEINS3(CI,CO,X,TB,ACC,GA, A,IDX,Wt,C,M) \
  k_meinsum<CI,CO,X,TB,ACC,GA,true,false><<<dim3((unsigned)(((M)*(X)+63)/64)),dim3(256),0,stream>>>((A),(IDX),(Wt),(C),(M),nullptr,0,0,nullptr)
#define MEINSG(CI,CO,X,SP, A,Wt,C,M, Pp,POFF) \
  k_meinsum<CI,CO,X,false,false,false,SP,true><<<dim3((unsigned)(((M)*(X)+63)/64)),dim3(256),0,stream>>>((A),nullptr,(Wt),(C),(M),(Pp),96,(POFF),nullptr)
#define MLP2(SP,PR, RRp,W1p,W2p,H2p,P1p,P2p,M) \
  k_mlp2<SP,PR><<<dim3((unsigned)(((M)+63)/64)),dim3(256),0,stream>>>((RRp),rbfc,rbfw,(W1p),(W2p),(H2p),(P1p),(P2p),(M))
#define G256(n) dim3((unsigned)(((n)+255)/256)),dim3(256),0,stream
#define GW4(n) dim3((unsigned)(((n)+3)/4)),dim3(256),0,stream

extern "C" void kernel_launch(void* const* d_in, const int* in_sizes, int n_in,
                              void* d_out, int out_size, void* d_ws, size_t ws_size,
                              hipStream_t stream)
{
  const float* pos =(const float*)d_in[0];
  const float* atab=(const float*)d_in[1];
  const float* rbfc=(const float*)d_in[2];
  const float* rbfw=(const float*)d_in[3];
  const float* degW1=(const float*)d_in[4];
  const float* degW2=(const float*)d_in[5];
  const float* degW3=(const float*)d_in[6];
  const float* Wv0=(const float*)d_in[7];
  const float* Wv1=(const float*)d_in[8];
  const float* Wv2=(const float*)d_in[9];
  const float* Ws0=(const float*)d_in[10];
  const float* Ws1=(const float*)d_in[11];
  const float* Ws2=(const float*)d_in[12];
  const float* rW1=(const float*)d_in[13];
  const float* rW2=(const float*)d_in[14];
  const float* rW3=(const float*)d_in[15];
  const float* WaS=(const float*)d_in[16];
  const float* WaD=(const float*)d_in[17];
  const float* WaE=(const float*)d_in[18];
  const float* wab=(const float*)d_in[19];
  const float* ff1=(const float*)d_in[20];
  const float* ff2=(const float*)d_in[21];
  const float* fg1=(const float*)d_in[22];
  const float* fg2=(const float*)d_in[23];
  const float* fW1=(const float*)d_in[24];
  const float* fW2=(const float*)d_in[25];
  const float* lng=(const float*)d_in[26];
  const float* lnb=(const float*)d_in[27];
  const float* W0h=(const float*)d_in[28];
  const float* hout=(const float*)d_in[29];
  const int* natom=(const int*)d_in[30];
  const int* esrc=(const int*)d_in[31];
  const int* edst=(const int*)d_in[32];

  float* Wp=(float*)d_ws;
  size_t off=0;
  auto al=[&](size_t n)->float*{ float* q=Wp+off; off+=n; return q; };

  const size_t SLOT = (size_t)NN*480;
  unsigned short* CKB = (unsigned short*)al((9*SLOT+1)/2);
  float* FA0=al((size_t)NN*128); float* FA1=al((size_t)NN*192); float* FA2=al((size_t)NN*160);
  float* FB0=al((size_t)NN*128); float* FB1=al((size_t)NN*192); float* FB2=al((size_t)NN*160);
  float* DI0=al((size_t)NN*128); float* DI1=al((size_t)NN*192); float* DI2=al((size_t)NN*160);
  float* DY0=al((size_t)NN*128); float* DY1=al((size_t)NN*192); float* DY2=al((size_t)NN*160);
  float* U=al((size_t)NE*3); float* Rr=al(NE); float* SH2b=al((size_t)NE*5);
  float* ABLK=al(8ULL*NE); float* LAM=al(NE);
  float* SSUM=al(NN); float* ENODE=al(NN); float* SACC=al(NN);
  float* DRr=al(NE); float* DSH1=al((size_t)NE*3); float* DSH2=al((size_t)NE*5);
  float* DPOS=al((size_t)NN*3);
  float* WCATF=al(8ULL*128*352);
  float* WCATZ=al(8ULL*320*32);
  float* WCATG=al(8ULL*128*96);
  int* ROWS =(int*)al(NN+1);
  int* CNT  =(int*)al(NN);
  int* POSB =(int*)al(NN);
  int* PERMB=(int*)al(NE);
  int* ESRC2=(int*)al(NE);
  int* EDST2=(int*)al(NE);

  // ---- UNION region: per-phase chunk layouts + node-phase buffers (all time-disjoint) ----
  const size_t UNI = 28800000;
  float* UN = al(UNI);
  float* TBc=UN;
  float* DTc=TBc+(size_t)NNC*512;
  float* P12=DTc+(size_t)NNC*512;
  float* V1 =P12+(size_t)NN*96;
  float* V2 =V1 +(size_t)NN*192;
  float* DPb=V2 +(size_t)NN*160;
  float* F0N=DPb+(size_t)NN*96;

  float* outE=(float*)d_out;
  float* outF=outE+NG;

  if (off*sizeof(float) > ws_size){
    k_sentinel<<<G256(out_size)>>>(outE, out_size, (float)ws_size);
    return;
  }

  // ---------------- sort edges by dst ----------------
  (void)hipMemsetAsync(CNT,0,NN*sizeof(int),stream);
  k_hist<<<G256(NE)>>>(edst,CNT,NE);
  k_scan0<<<dim3(1),dim3(256),0,stream>>>(CNT,ROWS);
  (void)hipMemcpyAsync(POSB,ROWS,NN*sizeof(int),hipMemcpyDeviceToDevice,stream);
  k_fillperm<<<G256(NE)>>>(edst,POSB,PERMB,NE);
  k_mkedge<<<G256(NE)>>>(PERMB,esrc,edst,ESRC2,EDST2);
  k_wcat<<<G256(8*128*352)>>>(Wv0,Ws0,Ws1,Ws2,WCATF);
  k_wcatz<<<G256(8*320*32)>>>(WaS,WaD,WaE,WCATZ);
  k_wcatg<<<G256(8*128*96)>>>(fg1,fg2,WCATG);

  // ---------------- setup ----------------
  k_geom<<<G256(NE)>>>(pos,ESRC2,EDST2,U,Rr,SH2b);
  k_f0init<<<G256(NN*128)>>>(natom,atab,FA0);
  (void)hipMemsetAsync(FA1,0,(size_t)NN*352*4,stream);   // FA1+FA2 contiguous
  (void)hipMemsetAsync(DRr,0,(size_t)NE*4,stream);
  (void)hipMemsetAsync(DSH1,0,(size_t)NE*3*4,stream);
  (void)hipMemsetAsync(DSH2,0,(size_t)NE*5*4,stream);
  (void)hipMemsetAsync(DPOS,0,(size_t)NN*3*4,stream);

  // degree embedding (CHIF chunks) -> FA  [split-bf16 + fused RBF MLP]
  {
    float* H1=UN; float* H2=H1+(size_t)CHIF*64; float* Gc=H2+(size_t)CHIF*64;
    (void)H1;
    for (int cc=0;cc<NIF;cc++){
      int c0e=cc*CHIF, cnt=(c0e+CHIF<=NE)?CHIF:(NE-c0e);
      MLP2(true,false, Rr+c0e, degW1, degW2, H2, nullptr, nullptr, cnt);
      MGEMM3(64,false,false,0,false, H2,nullptr,degW3,Gc, cnt,224,64);
      k_agg<true><<<dim3(NG),dim3(512),0,stream>>>(FA0,FA1,FA2,
        nullptr,nullptr,nullptr, Gc,U,SH2b, nullptr, EDST2,EDST2, nullptr, c0e,c0e+cnt);
    }
  }
  k_q3<<<G256(NN*480)>>>(FA0,FA1,FA2, CKB);

  // forward feature buffers: f0 ping-pongs, f1/f2 stay
  float *c0_=FA0,*c1_=FA1,*c2_=FA2, *n0_=FB0,*n1_=FB1,*n2_=FB2;

  // ---------------- forward blocks [split-bf16], CHF chunks ----------------
  {
    float* H1  =UN;
    float* H2  =H1  +(size_t)CHF*64;
    float* Gc  =H2  +(size_t)CHF*64;
    float* SCAT=Gc  +(size_t)CHF*224;
    float* SV1 =SCAT+(size_t)CHF*352;
    float* SV2 =SV1 +(size_t)CHF*192;
    float* Zc  =SV2 +(size_t)CHF*160;
    (void)H1;
    for (int i=0;i<8;i++){
      const float* Wv1i=Wv1+(size_t)i*4096; const float* Wv2i=Wv2+(size_t)i*1024;
      const float* rW1i=rW1+(size_t)i*8192; const float* rW2i=rW2+(size_t)i*4096; const float* rW3i=rW3+(size_t)i*14336;
      const float* WZi=WCATZ+(size_t)i*10240;
      const float* ff1i=ff1+(size_t)i*65536; const float* ff2i=ff2+(size_t)i*65536;
      const float* fgCi=WCATG+(size_t)i*12288;
      const float* fW1i=fW1+(size_t)i*4096; const float* fW2i=fW2+(size_t)i*1024;
      const float* WCi=WCATF+(size_t)i*45056;
      float* AB=ABLK+(size_t)i*NE;

      (void)hipMemsetAsync(SACC,0,(size_t)NN*4,stream);
      (void)hipMemsetAsync(n0_,0,(size_t)NN*128*4,stream);
      (void)hipMemsetAsync(n1_,0,(size_t)NN*352*4,stream);   // n1_,n2_ = FB1,FB2 contiguous
      for (int cc=0;cc<NF;cc++){
        int c0e=cc*CHF, cnt=(c0e+CHF<=NE)?CHF:(NE-c0e);
        MLP2(true,false, Rr+c0e, rW1i, rW2i, H2, nullptr, nullptr, cnt);
        MGEMM3(64,false,false,0,false, H2,nullptr,rW3i,Gc, cnt,224,64);
        k_zgemm<true,true><<<dim3((unsigned)((cnt+63)/64)),dim3(256),0,stream>>>(
            c0_, ESRC2+c0e, EDST2+c0e, H2, WZi, wab+(size_t)i*32, Zc, LAM+c0e, cnt);
        MGEMM3(64,false,false,0,true, c0_,ESRC2+c0e,WCi,SCAT, cnt,352,128);
        MEINS3(64,64,3,false,false,true, c1_,ESRC2+c0e,Wv1i,SV1, cnt);
        MEINS3(32,32,5,false,false,true, c2_,ESRC2+c0e,Wv2i,SV2, cnt);
        k_agg<false><<<dim3(NG),dim3(512),0,stream>>>(n0_,n1_,n2_,
          SCAT,SV1,SV2, Gc,U,SH2b, LAM, EDST2,EDST2, SACC, c0e,c0e+cnt);
      }
      k_postblk<<<G256(NN*480)>>>(c0_,c1_,c2_, n0_,n1_,n2_, SACC, CKB+(size_t)(i+1)*SLOT, LAM, EDST2, AB);
      for (int nc=0;nc<NN/NNC;nc++){
        MGEMM3(64,false,false,1,false, n0_+(size_t)nc*NNC*128,nullptr,ff1i,TBc, NNC,512,128);
        MGEMM3(64,false,true, 0,false, TBc,nullptr,ff2i, n0_+(size_t)nc*NNC*128, NNC,128,512);
      }
      MGEMM3(64,false,false,3,false, n0_,nullptr,fgCi,P12, NN,96,128);
      MEINSG(64,64,3,true, n1_,fW1i,c1_, NN, P12, 0);   // c1_ = n1_ + V1*P(gate1)
      MEINSG(32,32,5,true, n2_,fW2i,c2_, NN, P12, 64);  // c2_ = n2_ + V2*P(gate2)
      float* t;
      t=c0_;c0_=n0_;n0_=t;   // only f0 ping-pongs
    }
  }

  // ---------------- head ----------------
  k_lnhead<<<dim3(NN),dim3(64),0,stream>>>(c0_,c1_,c2_, lng,lnb,W0h,hout, ENODE, DI0,DI1,DI2);
  k_esum<<<dim3(8),dim3(64),0,stream>>>(ENODE,outE);

  // ---------------- backward blocks [plain bf16 MFMA, fused epilogues], CHB chunks ----------------
  {
    float* PRE1=UN;
    float* PRE2=PRE1+(size_t)CHB*64;
    float* H1  =PRE2+(size_t)CHB*64;
    float* H2  =H1  +(size_t)CHB*64;
    float* Gc  =H2  +(size_t)CHB*64;
    float* DGc =Gc  +(size_t)CHB*224;
    float* SCAT=DGc +(size_t)CHB*224;
    float* SV1 =SCAT+(size_t)CHB*352;
    float* SV2 =SV1 +(size_t)CHB*192;
    float* Zc  =SV2 +(size_t)CHB*160;
    float* DE0 =PRE1;   // alias: PRE1+PRE2 (128/edge) dead after rW backward chain
    float* RBFc=DGc;    // alias: DGc dead after rW3^T read
    float* DZD =Gc;     // alias: Gc dead after k_bedge
    for (int i=7;i>=0;--i){
      const float* Wv1i=Wv1+(size_t)i*4096; const float* Wv2i=Wv2+(size_t)i*1024;
      const float* rW1i=rW1+(size_t)i*8192; const float* rW2i=rW2+(size_t)i*4096; const float* rW3i=rW3+(size_t)i*14336;
      const float* WZi=WCATZ+(size_t)i*10240;
      const float* WaSi=WaS+(size_t)i*4096; const float* WaDi=WaD+(size_t)i*4096; const float* WaEi=WaE+(size_t)i*2048;
      const float* ff1i=ff1+(size_t)i*65536; const float* ff2i=ff2+(size_t)i*65536;
      const float* fgCi=WCATG+(size_t)i*12288;
      const float* fW1i=fW1+(size_t)i*4096; const float* fW2i=fW2+(size_t)i*1024;
      const float* WCi=WCATF+(size_t)i*45056;
      const float* AB=ABLK+(size_t)i*NE;
      float *fa1=FA1, *fa2=FA2, *dy1=DY1, *dy2=DY2;

      k_dq3x2<<<G256(NN*480)>>>(CKB+(size_t)i*SLOT, CKB+(size_t)(i+1)*SLOT, FA0,FA1,FA2, FB0,FB1,FB2);
      if (i>0){
        const float* pf1=ff1+(size_t)(i-1)*65536; const float* pf2=ff2+(size_t)(i-1)*65536;
        const float* pgC=WCATG+(size_t)(i-1)*12288;
        const float* pW1=fW1+(size_t)(i-1)*4096; const float* pW2=fW2+(size_t)(i-1)*1024;
        for (int nc=0;nc<NN/NNC;nc++){
          MGEMM(64,false,false,1,false, FA0+(size_t)nc*NNC*128,nullptr,pf1,TBc, NNC,512,128);
          MGEMM(64,false,true, 0,false, TBc,nullptr,pf2, FA0+(size_t)nc*NNC*128, NNC,128,512);
        }
        MGEMM(64,false,false,3,false, FA0,nullptr,pgC,P12, NN,96,128);
        MEINSG(64,64,3,false, FA1,pW1,DY1, NN, P12, 0);   // DY1 = FA1 + V*P
        MEINSG(32,32,5,false, FA2,pW2,DY2, NN, P12, 64);
        fa1=DY1; dy1=FA1; fa2=DY2; dy2=FA2;               // swap roles
      }
      for (int nc=0;nc<NN/NNC;nc++){
        MGEMM(64,false,false,1,false, FB0+(size_t)nc*NNC*128,nullptr,ff1i,TBc, NNC,512,128);
        MGEMMD(64,false,true, 0,false, TBc,nullptr,ff2i, F0N+(size_t)nc*NNC*128, NNC,128,512, FB0+(size_t)nc*NNC*128);
      }
      MGEMM(64,false,false,3,false, F0N,nullptr,fgCi,P12, NN,96,128);
      MEINS(64,64,3,false,false,false, FB1,nullptr,fW1i,V1, NN);
      MEINS(32,32,5,false,false,false, FB2,nullptr,fW2i,V2, NN);
      k_gateback2<<<G256(NN*96)>>>(DI1,V1,DI2,V2,P12,DPb);
      MGEMM(64,true,true,0,false, DPb,nullptr,fgCi,DI0, NN,128,96);
      MEINSD(64,64,3,true,true,false, V1,nullptr,fW1i,dy1, NN, DI1);
      MEINSD(32,32,5,true,true,false, V2,nullptr,fW2i,dy2, NN, DI2);
      for (int nc=0;nc<NN/NNC;nc++){
        MGEMM(64,false,false,0,false, FB0+(size_t)nc*NNC*128,nullptr,ff1i,TBc, NNC,512,128);
        MG(64,true,false,0,false, false,false,true,false, DI0+(size_t)nc*NNC*128,nullptr,ff2i,DTc, NNC,512,128, nullptr,nullptr,TBc,nullptr,nullptr);
        MGEMMD(64,true,true,0,false, DTc,nullptr,ff1i, DY0+(size_t)nc*NNC*128, NNC,128,512, DI0+(size_t)nc*NNC*128);
      }
      k_ssum<<<dim3(NN/4),dim3(256),0,stream>>>(FA0,fa1,fa2,FB0,FB1,FB2,DY0,dy1,dy2,SSUM, DI0,DI1,DI2);
      for (int cc=0;cc<NB;cc++){
        int c0e=cc*CHB, cnt=(c0e+CHB<=NE)?CHB:(NE-c0e);
        MLP2(false,true, Rr+c0e, rW1i, rW2i, H2, PRE1, PRE2, cnt);
        MGEMM(64,false,false,0,false, H2,nullptr,rW3i,Gc, cnt,224,64);
        k_zgemm<false,false><<<dim3((unsigned)((cnt+63)/64)),dim3(256),0,stream>>>(
            FA0, ESRC2+c0e, EDST2+c0e, H2, WZi, nullptr, Zc, nullptr, cnt);
        MGEMM(64,false,false,0,true, FA0,ESRC2+c0e,WCi,SCAT, cnt,352,128);
        MEINS(64,64,3,false,false,true, fa1,ESRC2+c0e,Wv1i,SV1, cnt);
        MEINS(32,32,5,false,false,true, fa2,ESRC2+c0e,Wv2i,SV2, cnt);
        k_bedge<<<GW4(cnt)>>>(SCAT,SV1,SV2, Gc,U,SH2b, DY0,dy1,dy2, EDST2, SSUM,
                              wab+(size_t)i*32, Zc, AB, DGc, DSH1, DSH2, c0e, cnt);
        // rW backward chain first (consumes PRE1/PRE2, DGc) ...
        MGEMM(64,true,false,0,false, Zc,nullptr,WaEi,H2, cnt,64,32);
        MG(64,true,true,0,false, false,false,true,false, DGc,nullptr,rW3i,H2, cnt,64,224, nullptr,nullptr,PRE2,nullptr,nullptr);
        MG(64,true,false,0,false, false,false,true,false, H2,nullptr,rW2i,H1, cnt,64,64, nullptr,nullptr,PRE1,nullptr,nullptr);
        MGEMM(64,true,false,0,false, H1,nullptr,rW1i,RBFc, cnt,128,64);
        k_dr<<<GW4(cnt)>>>(RBFc,Rr,rbfc,rbfw,DRr, c0e,cnt);
        // ... then edge-grad group into freed regions
        MGEMM(64,true,false,0,false, SCAT,nullptr,WCi,DE0, cnt,128,352);
        MGEMM(64,true,true, 0,false, Zc,nullptr,WaSi,DE0, cnt,128,32);
        MGEMM(64,true,false,0,false, Zc,nullptr,WaDi,DZD, cnt,128,32);
        MEINS(64,64,3,true,false,false, SV1,nullptr,Wv1i,SV1, cnt);
        MEINS(32,32,5,true,false,false, SV2,nullptr,Wv2i,SV2, cnt);
        k_scat<<<dim3(NG),dim3(640),0,stream>>>(DI0,DI1,DI2, DE0,DZD,SV1,SV2, ESRC2,EDST2, c0e,c0e+cnt);
      }
    }
  }

  // ---------------- initial embedding backward [fused], CHIB chunks ----------------
  {
    float* PRE1=UN;
    float* PRE2=PRE1+(size_t)CHIB*64;
    float* H1  =PRE2+(size_t)CHIB*64;
    float* H2  =H1  +(size_t)CHIB*64;
    float* Gc  =H2  +(size_t)CHIB*64;
    float* DGc =Gc  +(size_t)CHIB*224;
    float* RBFc=DGc +(size_t)CHIB*224;
    (void)H1;
    for (int cc=0;cc<NIB;cc++){
      int c0e=cc*CHIB, cnt=(c0e+CHIB<=NE)?CHIB:(NE-c0e);
      MLP2(false,true, Rr+c0e, degW1, degW2, H2, PRE1, PRE2, cnt);
      MGEMM(64,false,false,0,false, H2,nullptr,degW3,Gc, cnt,224,64);
      k_initback<<<GW4(cnt)>>>(DI0,DI1,DI2,EDST2,Gc,U,SH2b,DGc,DSH1,DSH2, c0e,cnt);
      MG(64,true,false,0,false, false,false,true,false, DGc,nullptr,degW3,H2, cnt,64,224, nullptr,nullptr,PRE2,nullptr,nullptr);
      MG(64,true,false,0,false, false,false,true,false, H2,nullptr,degW2,H1, cnt,64,64, nullptr,nullptr,PRE1,nullptr,nullptr);
      MGEMM(64,true,false,0,false, H1,nullptr,degW1,RBFc, cnt,128,64);
      k_dr<<<GW4(cnt)>>>(RBFc,Rr,rbfc,rbfw,DRr, c0e,cnt);
    }
  }

  // ---------------- geometry backward + outputs ----------------
  k_geoback<<<G256(NE)>>>(DRr,DSH1,DSH2,U,Rr,ESRC2,EDST2,DPOS);
  k_forces<<<G256(NN*3)>>>(DPOS,outF);
  (void)in_sizes; (void)n_in; (void)out_size;
}